// Round 3
// baseline (1283.237 us; speedup 1.0000x reference)
//
#include <hip/hip_runtime.h>
#include <hip/hip_bf16.h>
#include <stdint.h>

#define N_NODES 50000
#define N_EDGES 800000
#define K_KEEP  40000

typedef unsigned long long u64;
typedef unsigned int u32;

struct Ctl {
  u64 prefix;
  u32 kremain;
  u32 cnt;
  float inv_norm;
  u32 isfp32;
  u32 fail;
  u32 pad;
  u32 hist[256];
  float colsum[64];
};

__device__ __forceinline__ float bf2f(__hip_bfloat16 v) { return __bfloat162float(v); }
__device__ __forceinline__ float loadF(const void* p, size_t i, bool f32) {
  return f32 ? ((const float*)p)[i] : bf2f(((const __hip_bfloat16*)p)[i]);
}

// ---------------- init / detect ----------------

__global__ void init_kernel(float* __restrict__ deg1, float* __restrict__ deg2, Ctl* ctl) {
  int i = blockIdx.x * 256 + threadIdx.x;
  if (i < N_NODES) deg1[i] = 1.0f;
  if (i < K_KEEP)  deg2[i] = 1.0f;
  if (blockIdx.x == 0) {
    ctl->hist[threadIdx.x] = 0u;
    if (threadIdx.x < 64) ctl->colsum[threadIdx.x] = 0.0f;
    if (threadIdx.x == 0) { ctl->prefix = 0ull; ctl->kremain = K_KEEP; ctl->cnt = 0u; ctl->fail = 0u; }
  }
}

// count bf16 exp==0xFF patterns in first 131072 halfwords of x:
// real bf16 data -> 0; fp32 data read as halfwords -> ~256 (mantissa junk).
__global__ void detect_kernel(const void* __restrict__ x, Ctl* ctl) {
  __shared__ u32 sh[256];
  const unsigned short* p = (const unsigned short*)x;
  u32 c = 0;
  for (int i = threadIdx.x; i < 131072; i += 256) {
    u32 h = p[i];
    if ((h & 0x7F80u) == 0x7F80u) c++;
  }
  sh[threadIdx.x] = c;
  __syncthreads();
  for (int s = 128; s > 0; s >>= 1) {
    if (threadIdx.x < s) sh[threadIdx.x] += sh[threadIdx.x + s];
    __syncthreads();
  }
  if (threadIdx.x == 0) ctl->isfp32 = (sh[0] >= 16u) ? 1u : 0u;
}

__global__ void norm_kernel(const void* __restrict__ pw, Ctl* ctl) {
  bool f32 = ctl->isfp32 != 0;
  int lane = threadIdx.x;   // 64 threads
  float v0 = loadF(pw, lane, f32);
  float v1 = loadF(pw, 64 + lane, f32);
  float s = v0 * v0 + v1 * v1;
  for (int off = 32; off; off >>= 1) s += __shfl_down(s, off);
  if (lane == 0) ctl->inv_norm = 1.0f / sqrtf(s);
}

__global__ void degcount_kernel(const int* __restrict__ dst, float* __restrict__ deg) {
  int e = blockIdx.x * 256 + threadIdx.x;
  if (e < N_EDGES) atomicAdd(&deg[dst[e]], 1.0f);
}

// ---------------- GEMMs (concrete, no templates) ----------------

// conv1: Y[M,128] = X[M,64] @ W[64,128], X read via dtype flag
__global__ void gemm_in_kernel(const void* __restrict__ Xv, const void* __restrict__ W,
                               float* __restrict__ Y, const Ctl* __restrict__ ctl)
{
  __shared__ float Ws[64 * 128];   // 32KB
  __shared__ float Xs[32 * 64];    // 8KB
  const bool f32 = ctl->isfp32 != 0;
  const int tid = threadIdx.x;
  const int row0 = blockIdx.x * 32;

  for (int i = tid; i < 64 * 128; i += 256) Ws[i] = loadF(W, i, f32);
  for (int i = tid; i < 32 * 64; i += 256) {
    int r = i >> 6, k = i & 63;
    int gr = row0 + r;
    Xs[i] = (gr < N_NODES) ? loadF(Xv, (size_t)gr * 64 + k, f32) : 0.0f;
  }
  __syncthreads();

  const int tx = tid & 63;       // 64 col-threads, 2 cols each
  const int ty = tid >> 6;       // 4 row groups x 8 rows
  float acc[8][2];
  #pragma unroll
  for (int i = 0; i < 8; ++i) { acc[i][0] = 0.f; acc[i][1] = 0.f; }
  for (int k = 0; k < 64; ++k) {
    float w0 = Ws[k * 128 + tx];
    float w1 = Ws[k * 128 + tx + 64];
    #pragma unroll
    for (int i = 0; i < 8; ++i) {
      float xv = Xs[(ty * 8 + i) * 64 + k];
      acc[i][0] += xv * w0;
      acc[i][1] += xv * w1;
    }
  }
  #pragma unroll
  for (int i = 0; i < 8; ++i) {
    int gr = row0 + ty * 8 + i;
    if (gr < N_NODES) {
      Y[(size_t)gr * 128 + tx]      = acc[i][0];
      Y[(size_t)gr * 128 + tx + 64] = acc[i][1];
    }
  }
}

// Y[M,64] = (relu?)X[M,128] @ W[128,64]
__global__ void gemm_128_64_kernel(const float* __restrict__ X, const void* __restrict__ W,
                                   float* __restrict__ Y, const Ctl* __restrict__ ctl,
                                   int M, int relu_x)
{
  __shared__ float Ws[128 * 64];   // 32KB
  __shared__ float Xs[32 * 128];   // 16KB
  const bool f32 = ctl->isfp32 != 0;
  const int tid = threadIdx.x;
  const int row0 = blockIdx.x * 32;

  for (int i = tid; i < 128 * 64; i += 256) Ws[i] = loadF(W, i, f32);
  for (int i = tid; i < 32 * 128; i += 256) {
    int r = i >> 7, k = i & 127;
    int gr = row0 + r;
    float v = (gr < M) ? X[(size_t)gr * 128 + k] : 0.0f;
    if (relu_x) v = fmaxf(v, 0.0f);
    Xs[i] = v;
  }
  __syncthreads();

  const int tx = tid & 31;       // 32 col-threads, 2 cols each
  const int ty = tid >> 5;       // 8 row groups x 4 rows
  float acc[4][2];
  #pragma unroll
  for (int i = 0; i < 4; ++i) { acc[i][0] = 0.f; acc[i][1] = 0.f; }
  for (int k = 0; k < 128; ++k) {
    float w0 = Ws[k * 64 + tx];
    float w1 = Ws[k * 64 + tx + 32];
    #pragma unroll
    for (int i = 0; i < 4; ++i) {
      float xv = Xs[(ty * 4 + i) * 128 + k];
      acc[i][0] += xv * w0;
      acc[i][1] += xv * w1;
    }
  }
  #pragma unroll
  for (int i = 0; i < 4; ++i) {
    int gr = row0 + ty * 4 + i;
    if (gr < M) {
      Y[(size_t)gr * 64 + tx]      = acc[i][0];
      Y[(size_t)gr * 64 + tx + 32] = acc[i][1];
    }
  }
}

// Y[M,128] = (relu?)X[M,64] @ W[64,128]
__global__ void gemm_64_128_kernel(const float* __restrict__ X, const void* __restrict__ W,
                                   float* __restrict__ Y, const Ctl* __restrict__ ctl,
                                   int M, int relu_x)
{
  __shared__ float Ws[64 * 128];   // 32KB
  __shared__ float Xs[32 * 64];    // 8KB
  const bool f32 = ctl->isfp32 != 0;
  const int tid = threadIdx.x;
  const int row0 = blockIdx.x * 32;

  for (int i = tid; i < 64 * 128; i += 256) Ws[i] = loadF(W, i, f32);
  for (int i = tid; i < 32 * 64; i += 256) {
    int r = i >> 6, k = i & 63;
    int gr = row0 + r;
    float v = (gr < M) ? X[(size_t)gr * 64 + k] : 0.0f;
    if (relu_x) v = fmaxf(v, 0.0f);
    Xs[i] = v;
  }
  __syncthreads();

  const int tx = tid & 63;
  const int ty = tid >> 6;
  float acc[8][2];
  #pragma unroll
  for (int i = 0; i < 8; ++i) { acc[i][0] = 0.f; acc[i][1] = 0.f; }
  for (int k = 0; k < 64; ++k) {
    float w0 = Ws[k * 128 + tx];
    float w1 = Ws[k * 128 + tx + 64];
    #pragma unroll
    for (int i = 0; i < 8; ++i) {
      float xv = Xs[(ty * 8 + i) * 64 + k];
      acc[i][0] += xv * w0;
      acc[i][1] += xv * w1;
    }
  }
  #pragma unroll
  for (int i = 0; i < 8; ++i) {
    int gr = row0 + ty * 8 + i;
    if (gr < M) {
      Y[(size_t)gr * 128 + tx]      = acc[i][0];
      Y[(size_t)gr * 128 + tx + 64] = acc[i][1];
    }
  }
}

// sentinel: did gemm1 actually write? (ws poison is 0xAA)
__global__ void sentinel_kernel(const float* __restrict__ bufA, Ctl* ctl) {
  if (threadIdx.x < 4 && __float_as_uint(bufA[threadIdx.x]) == 0xAAAAAAAAu)
    atomicOr(&ctl->fail, 1u);
}

// ---------------- GCN aggregation ----------------

__global__ void agg_init_kernel(const float* __restrict__ hW, const float* __restrict__ deg,
                                const void* __restrict__ b, float* __restrict__ agg,
                                const Ctl* __restrict__ ctl, int M, int log2C)
{
  bool f32 = ctl->isfp32 != 0;
  int idx = blockIdx.x * 256 + threadIdx.x;
  if (idx >= (M << log2C)) return;
  int c = idx & ((1 << log2C) - 1);
  int r = idx >> log2C;
  agg[idx] = hW[idx] * (1.0f / deg[r]) + loadF(b, c, f32);
}

__global__ void agg_edges128_kernel(const float* __restrict__ hW, const float* __restrict__ deg,
                                    const int* __restrict__ src, const int* __restrict__ dst,
                                    float* __restrict__ agg)
{
  int gid = blockIdx.x * 256 + threadIdx.x;
  int wave = gid >> 6;
  int lane = gid & 63;
  int e0 = wave * 8;
  for (int j = 0; j < 8; ++j) {
    int e = e0 + j;
    if (e >= N_EDGES) return;
    int s = src[e], d = dst[e];
    if (s < 0 || d < 0) continue;
    float w = (1.0f / sqrtf(deg[s])) * (1.0f / sqrtf(deg[d]));
    atomicAdd(&agg[(size_t)d * 128 + lane],      w * hW[(size_t)s * 128 + lane]);
    atomicAdd(&agg[(size_t)d * 128 + 64 + lane], w * hW[(size_t)s * 128 + 64 + lane]);
  }
}

__global__ void agg_edges64_kernel(const float* __restrict__ hW, const float* __restrict__ deg,
                                   const int* __restrict__ src, const int* __restrict__ dst,
                                   float* __restrict__ agg)
{
  int gid = blockIdx.x * 256 + threadIdx.x;
  int wave = gid >> 6;
  int lane = gid & 63;
  int e0 = wave * 8;
  for (int j = 0; j < 8; ++j) {
    int e = e0 + j;
    if (e >= N_EDGES) return;
    int s = src[e], d = dst[e];
    if (s < 0 || d < 0) continue;
    float w = (1.0f / sqrtf(deg[s])) * (1.0f / sqrtf(deg[d]));
    atomicAdd(&agg[(size_t)d * 64 + lane], w * hW[(size_t)s * 64 + lane]);
  }
}

// ---------------- TopK pooling ----------------

__global__ void score_kernel(const float* __restrict__ h, const void* __restrict__ pw,
                             const Ctl* __restrict__ ctl, float* __restrict__ score,
                             u64* __restrict__ keys)
{
  bool f32 = ctl->isfp32 != 0;
  int gid = blockIdx.x * 256 + threadIdx.x;
  int row = gid >> 6;
  int lane = gid & 63;
  if (row >= N_NODES) return;
  float a0 = fmaxf(h[(size_t)row * 128 + lane], 0.f) * loadF(pw, lane, f32);
  float a1 = fmaxf(h[(size_t)row * 128 + 64 + lane], 0.f) * loadF(pw, 64 + lane, f32);
  float s = a0 + a1;
  for (int off = 32; off; off >>= 1) s += __shfl_down(s, off);
  if (lane == 0) {
    float sc = tanhf(s * ctl->inv_norm);
    score[row] = sc;
    u32 u = __float_as_uint(sc);
    u = (u & 0x80000000u) ? ~u : (u | 0x80000000u);
    keys[row] = (((u64)u) << 32) | (u64)(0xFFFFFFFFu - (u32)row);
  }
}

__global__ void hist_kernel(const u64* __restrict__ keys, Ctl* ctl, int shift) {
  __shared__ u32 lh[256];
  lh[threadIdx.x] = 0;
  __syncthreads();
  u64 prefix = ctl->prefix;
  int i = blockIdx.x * 256 + threadIdx.x;
  if (i < N_NODES) {
    u64 key = keys[i];
    bool match = (shift == 56) ? true : ((key >> (shift + 8)) == (prefix >> (shift + 8)));
    if (match) atomicAdd(&lh[(u32)((key >> shift) & 0xFF)], 1u);
  }
  __syncthreads();
  u32 c = lh[threadIdx.x];
  if (c) atomicAdd(&ctl->hist[threadIdx.x], c);
}

__global__ void pick_kernel(Ctl* ctl, int shift) {
  if (threadIdx.x == 0) {
    u32 kr = ctl->kremain;
    u32 cum = 0;
    int sel = 0;
    for (int v = 255; v >= 0; --v) {
      u32 c = ctl->hist[v];
      if (cum + c >= kr) { sel = v; break; }
      cum += c;
    }
    ctl->prefix |= ((u64)sel) << shift;
    ctl->kremain = kr - cum;
  }
  __syncthreads();
  ctl->hist[threadIdx.x] = 0;
}

__global__ void mark_kernel(const u64* __restrict__ keys, Ctl* ctl,
                            int* __restrict__ new_idx, int* __restrict__ kept)
{
  int i = blockIdx.x * 256 + threadIdx.x;
  if (i >= N_NODES) return;
  if (keys[i] >= ctl->prefix) {
    int pos = (int)atomicAdd(&ctl->cnt, 1u);
    new_idx[i] = pos;
    kept[pos] = i;
  } else {
    new_idx[i] = -1;
  }
}

__global__ void hp_kernel(const float* __restrict__ h, const int* __restrict__ kept,
                          const float* __restrict__ score, float* __restrict__ hp)
{
  int gid = blockIdx.x * 256 + threadIdx.x;
  int row = gid >> 6;
  int lane = gid & 63;
  if (row >= K_KEEP) return;
  int o = kept[row];
  float s = score[o];
  hp[(size_t)row * 128 + lane]      = fmaxf(h[(size_t)o * 128 + lane], 0.f) * s;
  hp[(size_t)row * 128 + 64 + lane] = fmaxf(h[(size_t)o * 128 + 64 + lane], 0.f) * s;
}

__global__ void remap_kernel(const int* __restrict__ src, const int* __restrict__ dst,
                             const int* __restrict__ new_idx, int* __restrict__ ns2,
                             int* __restrict__ nd2, float* __restrict__ deg2)
{
  int e = blockIdx.x * 256 + threadIdx.x;
  if (e >= N_EDGES) return;
  int s = new_idx[src[e]];
  int d = new_idx[dst[e]];
  ns2[e] = s; nd2[e] = d;
  if (s >= 0 && d >= 0) atomicAdd(&deg2[d], 1.0f);
}

// ---------------- mean pool ----------------

__global__ void colsum_kernel(const float* __restrict__ h4, Ctl* ctl) {
  int c = threadIdx.x & 63;
  int rg = blockIdx.x * 4 + (threadIdx.x >> 6);
  float acc = 0.f;
  for (int r = rg; r < K_KEEP; r += 512) acc += h4[(size_t)r * 64 + c];
  atomicAdd(&ctl->colsum[c], acc);
}

__global__ void finalize_kernel(const Ctl* __restrict__ ctl, void* __restrict__ out) {
  int c = threadIdx.x; // 64
  float val = ctl->colsum[c] / (float)K_KEEP;
  if (ctl->fail) val = 77.0f + 10.0f * (float)ctl->isfp32;  // diagnostic signal
  if (ctl->isfp32) ((float*)out)[c] = val;
  else             ((__hip_bfloat16*)out)[c] = __float2bfloat16(val);
}

// ---------------- launch ----------------

extern "C" void kernel_launch(void* const* d_in, const int* in_sizes, int n_in,
                              void* d_out, int out_size, void* d_ws, size_t ws_size,
                              hipStream_t stream)
{
  const void* x  = d_in[0];
  const int*  ei = (const int*)d_in[1];
  const void* W1 = d_in[3];
  const void* b1 = d_in[4];
  const void* pw = d_in[5];
  const void* W2 = d_in[6];
  const void* b2 = d_in[7];
  const void* W3 = d_in[8];
  const void* b3 = d_in[9];
  const void* W4 = d_in[10];
  const void* b4 = d_in[11];

  const int* src = ei;
  const int* dst = ei + N_EDGES;

  float* F = (float*)d_ws;
  float* BufA   = F;                       // N x 128
  float* BufB   = F + 6400000;             // N x 128
  float* BufC   = F + 12800000;            // K x 128
  float* deg1   = F + 17920000;
  float* deg2   = F + 17970000;
  float* score  = F + 18010000;
  u64*   keys   = (u64*)(F + 18060000);
  int*   new_idx= (int*)(F + 18160000);
  int*   kept   = (int*)(F + 18210000);
  int*   ns2    = (int*)(F + 18250000);
  int*   nd2    = (int*)(F + 19050000);
  Ctl*   ctl    = (Ctl*)(F + 19850000);

  const int ew_blocks = ((N_EDGES + 7) / 8 * 64 + 255) / 256; // 25000

  init_kernel<<<(N_NODES + 255) / 256, 256, 0, stream>>>(deg1, deg2, ctl);
  detect_kernel<<<1, 256, 0, stream>>>(x, ctl);
  norm_kernel<<<1, 64, 0, stream>>>(pw, ctl);
  degcount_kernel<<<(N_EDGES + 255) / 256, 256, 0, stream>>>(dst, deg1);

  // conv1
  gemm_in_kernel<<<(N_NODES + 31) / 32, 256, 0, stream>>>(x, W1, BufA, ctl);
  sentinel_kernel<<<1, 64, 0, stream>>>(BufA, ctl);
  agg_init_kernel<<<(N_NODES * 128 + 255) / 256, 256, 0, stream>>>(BufA, deg1, b1, BufB, ctl, N_NODES, 7);
  agg_edges128_kernel<<<ew_blocks, 256, 0, stream>>>(BufA, deg1, src, dst, BufB);

  // pooling
  score_kernel<<<(N_NODES + 3) / 4, 256, 0, stream>>>(BufB, pw, ctl, score, keys);
  for (int p = 0; p < 8; ++p) {
    int shift = 56 - 8 * p;
    hist_kernel<<<(N_NODES + 255) / 256, 256, 0, stream>>>(keys, ctl, shift);
    pick_kernel<<<1, 256, 0, stream>>>(ctl, shift);
  }
  mark_kernel<<<(N_NODES + 255) / 256, 256, 0, stream>>>(keys, ctl, new_idx, kept);
  hp_kernel<<<(K_KEEP + 3) / 4, 256, 0, stream>>>(BufB, kept, score, BufC);
  remap_kernel<<<(N_EDGES + 255) / 256, 256, 0, stream>>>(src, dst, new_idx, ns2, nd2, deg2);

  // conv2
  gemm_128_64_kernel<<<(K_KEEP + 31) / 32, 256, 0, stream>>>(BufC, W2, BufA, ctl, K_KEEP, 0);
  agg_init_kernel<<<(K_KEEP * 64 + 255) / 256, 256, 0, stream>>>(BufA, deg2, b2, BufC, ctl, K_KEEP, 6);
  agg_edges64_kernel<<<ew_blocks, 256, 0, stream>>>(BufA, deg2, ns2, nd2, BufC);

  // conv3
  gemm_64_128_kernel<<<(K_KEEP + 31) / 32, 256, 0, stream>>>(BufC, W3, BufA, ctl, K_KEEP, 1);
  agg_init_kernel<<<(K_KEEP * 128 + 255) / 256, 256, 0, stream>>>(BufA, deg2, b3, BufB, ctl, K_KEEP, 7);
  agg_edges128_kernel<<<ew_blocks, 256, 0, stream>>>(BufA, deg2, ns2, nd2, BufB);

  // conv4
  gemm_128_64_kernel<<<(K_KEEP + 31) / 32, 256, 0, stream>>>(BufB, W4, BufA, ctl, K_KEEP, 1);
  agg_init_kernel<<<(K_KEEP * 64 + 255) / 256, 256, 0, stream>>>(BufA, deg2, b4, BufC, ctl, K_KEEP, 6);
  agg_edges64_kernel<<<ew_blocks, 256, 0, stream>>>(BufA, deg2, ns2, nd2, BufC);

  // mean
  colsum_kernel<<<128, 256, 0, stream>>>(BufC, ctl);
  finalize_kernel<<<1, 64, 0, stream>>>(ctl, d_out);
}

// Round 4
// 1054.881 us; speedup vs baseline: 1.2165x; 1.2165x over previous
//
#include <hip/hip_runtime.h>
#include <hip/hip_bf16.h>
#include <stdint.h>

#define N_NODES 50000
#define N_EDGES 800000
#define K_KEEP  40000

typedef unsigned long long u64;
typedef unsigned int u32;

struct Ctl {
  u64 prefix;
  u32 kremain;
  u32 cnt;
  float inv_norm;
  u32 isfp32;
  u32 pad[2];
  u32 hist[256];
  float colsum[64];
};

__device__ __forceinline__ float bf2f(__hip_bfloat16 v) { return __bfloat162float(v); }
__device__ __forceinline__ float loadF(const void* p, size_t i, bool f32) {
  return f32 ? ((const float*)p)[i] : bf2f(((const __hip_bfloat16*)p)[i]);
}

// ---------------- init / detect ----------------

__global__ void init_kernel(int* __restrict__ cnt1, int* __restrict__ cnt2, Ctl* ctl) {
  int i = blockIdx.x * 256 + threadIdx.x;
  if (i < N_NODES) cnt1[i] = 0;
  if (i < K_KEEP)  cnt2[i] = 0;
  if (blockIdx.x == 0) {
    ctl->hist[threadIdx.x] = 0u;
    if (threadIdx.x < 64) ctl->colsum[threadIdx.x] = 0.0f;
    if (threadIdx.x == 0) { ctl->prefix = 0ull; ctl->kremain = K_KEEP; ctl->cnt = 0u; }
  }
}

// bf16-vs-fp32 runtime detection (proven in R3): fp32 data read as halfwords
// shows ~1/256 exp==0xFF patterns; real bf16 N(0,1) shows none.
__global__ void detect_kernel(const void* __restrict__ x, Ctl* ctl) {
  __shared__ u32 sh[256];
  const unsigned short* p = (const unsigned short*)x;
  u32 c = 0;
  for (int i = threadIdx.x; i < 131072; i += 256) {
    u32 h = p[i];
    if ((h & 0x7F80u) == 0x7F80u) c++;
  }
  sh[threadIdx.x] = c;
  __syncthreads();
  for (int s = 128; s > 0; s >>= 1) {
    if (threadIdx.x < s) sh[threadIdx.x] += sh[threadIdx.x + s];
    __syncthreads();
  }
  if (threadIdx.x == 0) ctl->isfp32 = (sh[0] >= 16u) ? 1u : 0u;
}

__global__ void norm_kernel(const void* __restrict__ pw, Ctl* ctl) {
  bool f32 = ctl->isfp32 != 0;
  int lane = threadIdx.x;   // 64
  float v0 = loadF(pw, lane, f32);
  float v1 = loadF(pw, 64 + lane, f32);
  float s = v0 * v0 + v1 * v1;
  for (int off = 32; off; off >>= 1) s += __shfl_down(s, off);
  if (lane == 0) ctl->inv_norm = 1.0f / sqrtf(s);
}

// ---------------- CSR build ----------------

__global__ void csr_count1_kernel(const int* __restrict__ dst, int* __restrict__ cnt) {
  int e = blockIdx.x * 256 + threadIdx.x;
  if (e < N_EDGES) atomicAdd(&cnt[dst[e]], 1);
}

// exclusive scan of cnt[0..n) -> rowstart[0..n]; cnt becomes the fill cursor;
// dis[i] = rsqrt(1 + cnt[i]) (GCN degree with self-loop). Single 1024-thread block.
__global__ void scan_kernel(int* __restrict__ cnt, int* __restrict__ rowstart,
                            float* __restrict__ dis, int n) {
  __shared__ int part[1024];
  const int tid = threadIdx.x;
  const int chunk = (n + 1023) / 1024;
  const int lo = tid * chunk;
  const int hi = min(lo + chunk, n);
  int sum = 0;
  for (int i = lo; i < hi; ++i) sum += cnt[i];
  part[tid] = sum;
  __syncthreads();
  for (int off = 1; off < 1024; off <<= 1) {
    int v = (tid >= off) ? part[tid - off] : 0;
    __syncthreads();
    part[tid] += v;
    __syncthreads();
  }
  int run = (tid == 0) ? 0 : part[tid - 1];
  for (int i = lo; i < hi; ++i) {
    int c = cnt[i];
    rowstart[i] = run;
    cnt[i] = run;                     // cursor for fill
    dis[i] = rsqrtf(1.0f + (float)c);
    run += c;
  }
  if (hi == n) rowstart[n] = run;     // run == total for all trailing threads
}

__global__ void csr_fill1_kernel(const int* __restrict__ src, const int* __restrict__ dst,
                                 int* __restrict__ cur, int* __restrict__ csr) {
  int e = blockIdx.x * 256 + threadIdx.x;
  if (e >= N_EDGES) return;
  int pos = atomicAdd(&cur[dst[e]], 1);
  csr[pos] = src[e];
}

__global__ void csr_count2_kernel(const int* __restrict__ src, const int* __restrict__ dst,
                                  const int* __restrict__ new_idx, int* __restrict__ cnt) {
  int e = blockIdx.x * 256 + threadIdx.x;
  if (e >= N_EDGES) return;
  int s = new_idx[src[e]];
  int d = new_idx[dst[e]];
  if (s >= 0 && d >= 0) atomicAdd(&cnt[d], 1);
}

__global__ void csr_fill2_kernel(const int* __restrict__ src, const int* __restrict__ dst,
                                 const int* __restrict__ new_idx, int* __restrict__ cur,
                                 int* __restrict__ csr) {
  int e = blockIdx.x * 256 + threadIdx.x;
  if (e >= N_EDGES) return;
  int s = new_idx[src[e]];
  int d = new_idx[dst[e]];
  if (s < 0 || d < 0) return;
  int pos = atomicAdd(&cur[d], 1);
  csr[pos] = s;
}

// ---------------- GEMMs (unchanged from passing R3) ----------------

__global__ void gemm_in_kernel(const void* __restrict__ Xv, const void* __restrict__ W,
                               float* __restrict__ Y, const Ctl* __restrict__ ctl)
{
  __shared__ float Ws[64 * 128];
  __shared__ float Xs[32 * 64];
  const bool f32 = ctl->isfp32 != 0;
  const int tid = threadIdx.x;
  const int row0 = blockIdx.x * 32;

  for (int i = tid; i < 64 * 128; i += 256) Ws[i] = loadF(W, i, f32);
  for (int i = tid; i < 32 * 64; i += 256) {
    int r = i >> 6, k = i & 63;
    int gr = row0 + r;
    Xs[i] = (gr < N_NODES) ? loadF(Xv, (size_t)gr * 64 + k, f32) : 0.0f;
  }
  __syncthreads();

  const int tx = tid & 63;
  const int ty = tid >> 6;
  float acc[8][2];
  #pragma unroll
  for (int i = 0; i < 8; ++i) { acc[i][0] = 0.f; acc[i][1] = 0.f; }
  for (int k = 0; k < 64; ++k) {
    float w0 = Ws[k * 128 + tx];
    float w1 = Ws[k * 128 + tx + 64];
    #pragma unroll
    for (int i = 0; i < 8; ++i) {
      float xv = Xs[(ty * 8 + i) * 64 + k];
      acc[i][0] += xv * w0;
      acc[i][1] += xv * w1;
    }
  }
  #pragma unroll
  for (int i = 0; i < 8; ++i) {
    int gr = row0 + ty * 8 + i;
    if (gr < N_NODES) {
      Y[(size_t)gr * 128 + tx]      = acc[i][0];
      Y[(size_t)gr * 128 + tx + 64] = acc[i][1];
    }
  }
}

__global__ void gemm_128_64_kernel(const float* __restrict__ X, const void* __restrict__ W,
                                   float* __restrict__ Y, const Ctl* __restrict__ ctl,
                                   int M, int relu_x)
{
  __shared__ float Ws[128 * 64];
  __shared__ float Xs[32 * 128];
  const bool f32 = ctl->isfp32 != 0;
  const int tid = threadIdx.x;
  const int row0 = blockIdx.x * 32;

  for (int i = tid; i < 128 * 64; i += 256) Ws[i] = loadF(W, i, f32);
  for (int i = tid; i < 32 * 128; i += 256) {
    int r = i >> 7, k = i & 127;
    int gr = row0 + r;
    float v = (gr < M) ? X[(size_t)gr * 128 + k] : 0.0f;
    if (relu_x) v = fmaxf(v, 0.0f);
    Xs[i] = v;
  }
  __syncthreads();

  const int tx = tid & 31;
  const int ty = tid >> 5;
  float acc[4][2];
  #pragma unroll
  for (int i = 0; i < 4; ++i) { acc[i][0] = 0.f; acc[i][1] = 0.f; }
  for (int k = 0; k < 128; ++k) {
    float w0 = Ws[k * 64 + tx];
    float w1 = Ws[k * 64 + tx + 32];
    #pragma unroll
    for (int i = 0; i < 4; ++i) {
      float xv = Xs[(ty * 4 + i) * 128 + k];
      acc[i][0] += xv * w0;
      acc[i][1] += xv * w1;
    }
  }
  #pragma unroll
  for (int i = 0; i < 4; ++i) {
    int gr = row0 + ty * 4 + i;
    if (gr < M) {
      Y[(size_t)gr * 64 + tx]      = acc[i][0];
      Y[(size_t)gr * 64 + tx + 32] = acc[i][1];
    }
  }
}

__global__ void gemm_64_128_kernel(const float* __restrict__ X, const void* __restrict__ W,
                                   float* __restrict__ Y, const Ctl* __restrict__ ctl,
                                   int M, int relu_x)
{
  __shared__ float Ws[64 * 128];
  __shared__ float Xs[32 * 64];
  const bool f32 = ctl->isfp32 != 0;
  const int tid = threadIdx.x;
  const int row0 = blockIdx.x * 32;

  for (int i = tid; i < 64 * 128; i += 256) Ws[i] = loadF(W, i, f32);
  for (int i = tid; i < 32 * 64; i += 256) {
    int r = i >> 6, k = i & 63;
    int gr = row0 + r;
    float v = (gr < M) ? X[(size_t)gr * 64 + k] : 0.0f;
    if (relu_x) v = fmaxf(v, 0.0f);
    Xs[i] = v;
  }
  __syncthreads();

  const int tx = tid & 63;
  const int ty = tid >> 6;
  float acc[8][2];
  #pragma unroll
  for (int i = 0; i < 8; ++i) { acc[i][0] = 0.f; acc[i][1] = 0.f; }
  for (int k = 0; k < 64; ++k) {
    float w0 = Ws[k * 128 + tx];
    float w1 = Ws[k * 128 + tx + 64];
    #pragma unroll
    for (int i = 0; i < 8; ++i) {
      float xv = Xs[(ty * 8 + i) * 64 + k];
      acc[i][0] += xv * w0;
      acc[i][1] += xv * w1;
    }
  }
  #pragma unroll
  for (int i = 0; i < 8; ++i) {
    int gr = row0 + ty * 8 + i;
    if (gr < N_NODES) {
      Y[(size_t)gr * 128 + tx]      = acc[i][0];
      Y[(size_t)gr * 128 + tx + 64] = acc[i][1];
    }
  }
}

// ---------------- GCN aggregation: CSR gather (no atomics) ----------------

// one wave per dst node; lane covers 2 channels via float2 (128 ch)
__global__ void agg_gather128_kernel(const float* __restrict__ hW, const int* __restrict__ rowstart,
                                     const int* __restrict__ csr, const float* __restrict__ dis,
                                     const void* __restrict__ b, const Ctl* __restrict__ ctl,
                                     float* __restrict__ agg, int M)
{
  const bool f32 = ctl->isfp32 != 0;
  int gid = blockIdx.x * 256 + threadIdx.x;
  int d = gid >> 6;
  int lane = gid & 63;
  if (d >= M) return;
  const float2* H = (const float2*)hW;
  float dd = dis[d];
  float2 h = H[(size_t)d * 64 + lane];
  float self = dd * dd;
  float ax = h.x * self + loadF(b, 2 * lane, f32);
  float ay = h.y * self + loadF(b, 2 * lane + 1, f32);
  int i0 = rowstart[d], i1 = rowstart[d + 1];
  for (int i = i0; i < i1; ++i) {
    int s = csr[i];
    float w = dd * dis[s];
    float2 v = H[(size_t)s * 64 + lane];
    ax += w * v.x;
    ay += w * v.y;
  }
  float2 o; o.x = ax; o.y = ay;
  ((float2*)agg)[(size_t)d * 64 + lane] = o;
}

// one wave per dst node; lane = channel (64 ch)
__global__ void agg_gather64_kernel(const float* __restrict__ hW, const int* __restrict__ rowstart,
                                    const int* __restrict__ csr, const float* __restrict__ dis,
                                    const void* __restrict__ b, const Ctl* __restrict__ ctl,
                                    float* __restrict__ agg, int M)
{
  const bool f32 = ctl->isfp32 != 0;
  int gid = blockIdx.x * 256 + threadIdx.x;
  int d = gid >> 6;
  int lane = gid & 63;
  if (d >= M) return;
  float dd = dis[d];
  float a = hW[(size_t)d * 64 + lane] * (dd * dd) + loadF(b, lane, f32);
  int i0 = rowstart[d], i1 = rowstart[d + 1];
  for (int i = i0; i < i1; ++i) {
    int s = csr[i];
    a += (dd * dis[s]) * hW[(size_t)s * 64 + lane];
  }
  agg[(size_t)d * 64 + lane] = a;
}

// ---------------- TopK pooling ----------------

__global__ void score_kernel(const float* __restrict__ h, const void* __restrict__ pw,
                             const Ctl* __restrict__ ctl, float* __restrict__ score,
                             u64* __restrict__ keys)
{
  bool f32 = ctl->isfp32 != 0;
  int gid = blockIdx.x * 256 + threadIdx.x;
  int row = gid >> 6;
  int lane = gid & 63;
  if (row >= N_NODES) return;
  float a0 = fmaxf(h[(size_t)row * 128 + lane], 0.f) * loadF(pw, lane, f32);
  float a1 = fmaxf(h[(size_t)row * 128 + 64 + lane], 0.f) * loadF(pw, 64 + lane, f32);
  float s = a0 + a1;
  for (int off = 32; off; off >>= 1) s += __shfl_down(s, off);
  if (lane == 0) {
    float sc = tanhf(s * ctl->inv_norm);
    score[row] = sc;
    u32 u = __float_as_uint(sc);
    u = (u & 0x80000000u) ? ~u : (u | 0x80000000u);
    keys[row] = (((u64)u) << 32) | (u64)(0xFFFFFFFFu - (u32)row);
  }
}

__global__ void hist_kernel(const u64* __restrict__ keys, Ctl* ctl, int shift) {
  __shared__ u32 lh[256];
  lh[threadIdx.x] = 0;
  __syncthreads();
  u64 prefix = ctl->prefix;
  int i = blockIdx.x * 256 + threadIdx.x;
  if (i < N_NODES) {
    u64 key = keys[i];
    bool match = (shift == 56) ? true : ((key >> (shift + 8)) == (prefix >> (shift + 8)));
    if (match) atomicAdd(&lh[(u32)((key >> shift) & 0xFF)], 1u);
  }
  __syncthreads();
  u32 c = lh[threadIdx.x];
  if (c) atomicAdd(&ctl->hist[threadIdx.x], c);
}

__global__ void pick_kernel(Ctl* ctl, int shift) {
  if (threadIdx.x == 0) {
    u32 kr = ctl->kremain;
    u32 cum = 0;
    int sel = 0;
    for (int v = 255; v >= 0; --v) {
      u32 c = ctl->hist[v];
      if (cum + c >= kr) { sel = v; break; }
      cum += c;
    }
    ctl->prefix |= ((u64)sel) << shift;
    ctl->kremain = kr - cum;
  }
  __syncthreads();
  ctl->hist[threadIdx.x] = 0;
}

__global__ void mark_kernel(const u64* __restrict__ keys, Ctl* ctl,
                            int* __restrict__ new_idx, int* __restrict__ kept)
{
  int i = blockIdx.x * 256 + threadIdx.x;
  if (i >= N_NODES) return;
  if (keys[i] >= ctl->prefix) {
    int pos = (int)atomicAdd(&ctl->cnt, 1u);
    new_idx[i] = pos;
    kept[pos] = i;
  } else {
    new_idx[i] = -1;
  }
}

__global__ void hp_kernel(const float* __restrict__ h, const int* __restrict__ kept,
                          const float* __restrict__ score, float* __restrict__ hp)
{
  int gid = blockIdx.x * 256 + threadIdx.x;
  int row = gid >> 6;
  int lane = gid & 63;
  if (row >= K_KEEP) return;
  int o = kept[row];
  float s = score[o];
  hp[(size_t)row * 128 + lane]      = fmaxf(h[(size_t)o * 128 + lane], 0.f) * s;
  hp[(size_t)row * 128 + 64 + lane] = fmaxf(h[(size_t)o * 128 + 64 + lane], 0.f) * s;
}

// ---------------- mean pool ----------------

__global__ void colsum_kernel(const float* __restrict__ h4, Ctl* ctl) {
  int c = threadIdx.x & 63;
  int rg = blockIdx.x * 4 + (threadIdx.x >> 6);
  float acc = 0.f;
  for (int r = rg; r < K_KEEP; r += 512) acc += h4[(size_t)r * 64 + c];
  atomicAdd(&ctl->colsum[c], acc);
}

__global__ void finalize_kernel(const Ctl* __restrict__ ctl, void* __restrict__ out) {
  int c = threadIdx.x; // 64
  float val = ctl->colsum[c] / (float)K_KEEP;
  if (ctl->isfp32) ((float*)out)[c] = val;
  else             ((__hip_bfloat16*)out)[c] = __float2bfloat16(val);
}

// ---------------- launch ----------------

extern "C" void kernel_launch(void* const* d_in, const int* in_sizes, int n_in,
                              void* d_out, int out_size, void* d_ws, size_t ws_size,
                              hipStream_t stream)
{
  const void* x  = d_in[0];
  const int*  ei = (const int*)d_in[1];
  const void* W1 = d_in[3];
  const void* b1 = d_in[4];
  const void* pw = d_in[5];
  const void* W2 = d_in[6];
  const void* b2 = d_in[7];
  const void* W3 = d_in[8];
  const void* b3 = d_in[9];
  const void* W4 = d_in[10];
  const void* b4 = d_in[11];

  const int* src = ei;
  const int* dst = ei + N_EDGES;

  float* F = (float*)d_ws;
  float* BufA      = F;                      // N x 128
  float* BufB      = F + 6400000;            // N x 128
  float* BufC      = F + 12800000;           // K x 128
  float* dis1      = F + 17920000;           // 50000
  float* dis2      = F + 17970000;           // 40000
  float* score     = F + 18010000;           // 50000
  u64*   keys      = (u64*)(F + 18060000);   // 50000 u64
  int*   new_idx   = (int*)(F + 18160000);   // 50000
  int*   kept      = (int*)(F + 18210000);   // 40000
  int*   cnt1      = (int*)(F + 18250000);   // 50000 (count -> cursor)
  int*   rowstart1 = (int*)(F + 18300000);   // 50001
  int*   cnt2      = (int*)(F + 18350004);   // 40000 (count -> cursor)
  int*   rowstart2 = (int*)(F + 18390004);   // 40001
  int*   csr1      = (int*)(F + 18430008);   // 800000
  int*   csr2      = (int*)(F + 19230008);   // 800000
  Ctl*   ctl       = (Ctl*)(F + 20030008);   // ~1.3 KB; total ~80.2 MB

  const int EB = (N_EDGES + 255) / 256;      // 3125 edge blocks

  init_kernel<<<(N_NODES + 255) / 256, 256, 0, stream>>>(cnt1, cnt2, ctl);
  detect_kernel<<<1, 256, 0, stream>>>(x, ctl);
  norm_kernel<<<1, 64, 0, stream>>>(pw, ctl);

  // CSR for graph 1
  csr_count1_kernel<<<EB, 256, 0, stream>>>(dst, cnt1);
  scan_kernel<<<1, 1024, 0, stream>>>(cnt1, rowstart1, dis1, N_NODES);
  csr_fill1_kernel<<<EB, 256, 0, stream>>>(src, dst, cnt1, csr1);

  // conv1: h = relu(gcn(x, W1, b1))  [relu folded into consumers]
  gemm_in_kernel<<<(N_NODES + 31) / 32, 256, 0, stream>>>(x, W1, BufA, ctl);
  agg_gather128_kernel<<<(N_NODES + 3) / 4, 256, 0, stream>>>(BufA, rowstart1, csr1, dis1, b1, ctl, BufB, N_NODES);

  // pooling
  score_kernel<<<(N_NODES + 3) / 4, 256, 0, stream>>>(BufB, pw, ctl, score, keys);
  for (int p = 0; p < 8; ++p) {
    int shift = 56 - 8 * p;
    hist_kernel<<<(N_NODES + 255) / 256, 256, 0, stream>>>(keys, ctl, shift);
    pick_kernel<<<1, 256, 0, stream>>>(ctl, shift);
  }
  mark_kernel<<<(N_NODES + 255) / 256, 256, 0, stream>>>(keys, ctl, new_idx, kept);
  hp_kernel<<<(K_KEEP + 3) / 4, 256, 0, stream>>>(BufB, kept, score, BufC);

  // CSR for pooled graph
  csr_count2_kernel<<<EB, 256, 0, stream>>>(src, dst, new_idx, cnt2);
  scan_kernel<<<1, 1024, 0, stream>>>(cnt2, rowstart2, dis2, K_KEEP);
  csr_fill2_kernel<<<EB, 256, 0, stream>>>(src, dst, new_idx, cnt2, csr2);

  // conv2
  gemm_128_64_kernel<<<(K_KEEP + 31) / 32, 256, 0, stream>>>(BufC, W2, BufA, ctl, K_KEEP, 0);
  agg_gather64_kernel<<<(K_KEEP + 3) / 4, 256, 0, stream>>>(BufA, rowstart2, csr2, dis2, b2, ctl, BufC, K_KEEP);

  // conv3
  gemm_64_128_kernel<<<(K_KEEP + 31) / 32, 256, 0, stream>>>(BufC, W3, BufA, ctl, K_KEEP, 1);
  agg_gather128_kernel<<<(K_KEEP + 3) / 4, 256, 0, stream>>>(BufA, rowstart2, csr2, dis2, b3, ctl, BufB, K_KEEP);

  // conv4
  gemm_128_64_kernel<<<(K_KEEP + 31) / 32, 256, 0, stream>>>(BufB, W4, BufA, ctl, K_KEEP, 1);
  agg_gather64_kernel<<<(K_KEEP + 3) / 4, 256, 0, stream>>>(BufA, rowstart2, csr2, dis2, b4, ctl, BufC, K_KEEP);

  // mean
  colsum_kernel<<<128, 256, 0, stream>>>(BufC, ctl);
  finalize_kernel<<<1, 64, 0, stream>>>(ctl, d_out);
}

// Round 5
// 841.650 us; speedup vs baseline: 1.5247x; 1.2533x over previous
//
#include <hip/hip_runtime.h>
#include <hip/hip_bf16.h>
#include <stdint.h>

#define N_NODES 50000
#define N_EDGES 800000
#define K_KEEP  40000

typedef unsigned long long u64;
typedef unsigned int u32;

struct Ctl {
  u64 prefix;
  u32 kremain;
  u32 cnt;
  float inv_norm;
  u32 isfp32;
  u32 done;
  u32 pad;
  u32 hist[256];
  float colsum[64];
};

__device__ __forceinline__ float bf2f(__hip_bfloat16 v) { return __bfloat162float(v); }
__device__ __forceinline__ float loadF(const void* p, size_t i, bool f32) {
  return f32 ? ((const float*)p)[i] : bf2f(((const __hip_bfloat16*)p)[i]);
}

// ---------------- init / detect ----------------

__global__ void init_kernel(int* __restrict__ cnt1, int* __restrict__ cnt2, Ctl* ctl) {
  int i = blockIdx.x * 256 + threadIdx.x;
  if (i < N_NODES) cnt1[i] = 0;
  if (i < K_KEEP)  cnt2[i] = 0;
  if (blockIdx.x == 0) {
    ctl->hist[threadIdx.x] = 0u;
    if (threadIdx.x < 64) ctl->colsum[threadIdx.x] = 0.0f;
    if (threadIdx.x == 0) { ctl->prefix = 0ull; ctl->kremain = K_KEEP; ctl->cnt = 0u; ctl->done = 0u; }
  }
}

// bf16-vs-fp32 runtime detection (proven in R3): fp32 data read as halfwords
// shows ~1/256 exp==0xFF patterns; real bf16 N(0,1) shows none.
__global__ void detect_kernel(const void* __restrict__ x, Ctl* ctl) {
  __shared__ u32 sh[256];
  const unsigned short* p = (const unsigned short*)x;
  u32 c = 0;
  for (int i = threadIdx.x; i < 131072; i += 256) {
    u32 h = p[i];
    if ((h & 0x7F80u) == 0x7F80u) c++;
  }
  sh[threadIdx.x] = c;
  __syncthreads();
  for (int s = 128; s > 0; s >>= 1) {
    if (threadIdx.x < s) sh[threadIdx.x] += sh[threadIdx.x + s];
    __syncthreads();
  }
  if (threadIdx.x == 0) ctl->isfp32 = (sh[0] >= 16u) ? 1u : 0u;
}

__global__ void norm_kernel(const void* __restrict__ pw, Ctl* ctl) {
  bool f32 = ctl->isfp32 != 0;
  int lane = threadIdx.x;   // 64
  float v0 = loadF(pw, lane, f32);
  float v1 = loadF(pw, 64 + lane, f32);
  float s = v0 * v0 + v1 * v1;
  for (int off = 32; off; off >>= 1) s += __shfl_down(s, off);
  if (lane == 0) ctl->inv_norm = 1.0f / sqrtf(s);
}

// ---------------- CSR build ----------------

__global__ void csr_count1_kernel(const int* __restrict__ dst, int* __restrict__ cnt) {
  int e = blockIdx.x * 256 + threadIdx.x;
  if (e < N_EDGES) atomicAdd(&cnt[dst[e]], 1);
}

// hierarchical exclusive scan (R4 post-mortem: single-block scan was 134us at
// 0.14% occupancy; 3-phase coalesced version is ~memory cost, ~12us/graph)
__global__ void block_reduce_kernel(const int* __restrict__ cnt, int* __restrict__ bsum, int n) {
  __shared__ int sh[256];
  int i = blockIdx.x * 256 + threadIdx.x;
  sh[threadIdx.x] = (i < n) ? cnt[i] : 0;
  __syncthreads();
  for (int s = 128; s > 0; s >>= 1) {
    if (threadIdx.x < s) sh[threadIdx.x] += sh[threadIdx.x + s];
    __syncthreads();
  }
  if (threadIdx.x == 0) bsum[blockIdx.x] = sh[0];
}

__global__ void scan_bsum_kernel(const int* __restrict__ bsum, int* __restrict__ boff,
                                 int nb, int* __restrict__ rowstart_n) {
  __shared__ int sh[256];
  int tid = threadIdx.x;
  int v = (tid < nb) ? bsum[tid] : 0;
  sh[tid] = v;
  __syncthreads();
  for (int off = 1; off < 256; off <<= 1) {
    int t = (tid >= off) ? sh[tid - off] : 0;
    __syncthreads();
    sh[tid] += t;
    __syncthreads();
  }
  if (tid < nb) boff[tid] = sh[tid] - v;       // exclusive block offset
  if (tid == 255) *rowstart_n = sh[255];       // total valid edges
}

__global__ void block_scanout_kernel(int* __restrict__ cnt, const int* __restrict__ boff,
                                     int* __restrict__ rowstart, float* __restrict__ dis, int n) {
  __shared__ int sh[256];
  int tid = threadIdx.x;
  int i = blockIdx.x * 256 + tid;
  int c = (i < n) ? cnt[i] : 0;
  sh[tid] = c;
  __syncthreads();
  for (int off = 1; off < 256; off <<= 1) {
    int t = (tid >= off) ? sh[tid - off] : 0;
    __syncthreads();
    sh[tid] += t;
    __syncthreads();
  }
  if (i < n) {
    int pos = boff[blockIdx.x] + sh[tid] - c;  // exclusive prefix
    rowstart[i] = pos;
    cnt[i] = pos;                              // fill cursor
    dis[i] = rsqrtf(1.0f + (float)c);
  }
}

__global__ void csr_fill1_kernel(const int* __restrict__ src, const int* __restrict__ dst,
                                 int* __restrict__ cur, int* __restrict__ csr) {
  int e = blockIdx.x * 256 + threadIdx.x;
  if (e >= N_EDGES) return;
  int pos = atomicAdd(&cur[dst[e]], 1);
  csr[pos] = src[e];
}

__global__ void csr_count2_kernel(const int* __restrict__ src, const int* __restrict__ dst,
                                  const int* __restrict__ new_idx, int* __restrict__ cnt) {
  int e = blockIdx.x * 256 + threadIdx.x;
  if (e >= N_EDGES) return;
  int s = new_idx[src[e]];
  int d = new_idx[dst[e]];
  if (s >= 0 && d >= 0) atomicAdd(&cnt[d], 1);
}

__global__ void csr_fill2_kernel(const int* __restrict__ src, const int* __restrict__ dst,
                                 const int* __restrict__ new_idx, int* __restrict__ cur,
                                 int* __restrict__ csr) {
  int e = blockIdx.x * 256 + threadIdx.x;
  if (e >= N_EDGES) return;
  int s = new_idx[src[e]];
  int d = new_idx[dst[e]];
  if (s < 0 || d < 0) return;
  int pos = atomicAdd(&cur[d], 1);
  csr[pos] = s;
}

// ---------------- GEMMs ----------------

__global__ void gemm_in_kernel(const void* __restrict__ Xv, const void* __restrict__ W,
                               float* __restrict__ Y, const Ctl* __restrict__ ctl)
{
  __shared__ float Ws[64 * 128];
  __shared__ float Xs[32 * 64];
  const bool f32 = ctl->isfp32 != 0;
  const int tid = threadIdx.x;
  const int row0 = blockIdx.x * 32;

  for (int i = tid; i < 64 * 128; i += 256) Ws[i] = loadF(W, i, f32);
  for (int i = tid; i < 32 * 64; i += 256) {
    int r = i >> 6, k = i & 63;
    int gr = row0 + r;
    Xs[i] = (gr < N_NODES) ? loadF(Xv, (size_t)gr * 64 + k, f32) : 0.0f;
  }
  __syncthreads();

  const int tx = tid & 63;
  const int ty = tid >> 6;
  float acc[8][2];
  #pragma unroll
  for (int i = 0; i < 8; ++i) { acc[i][0] = 0.f; acc[i][1] = 0.f; }
  for (int k = 0; k < 64; ++k) {
    float w0 = Ws[k * 128 + tx];
    float w1 = Ws[k * 128 + tx + 64];
    #pragma unroll
    for (int i = 0; i < 8; ++i) {
      float xv = Xs[(ty * 8 + i) * 64 + k];
      acc[i][0] += xv * w0;
      acc[i][1] += xv * w1;
    }
  }
  #pragma unroll
  for (int i = 0; i < 8; ++i) {
    int gr = row0 + ty * 8 + i;
    if (gr < N_NODES) {
      Y[(size_t)gr * 128 + tx]      = acc[i][0];
      Y[(size_t)gr * 128 + tx + 64] = acc[i][1];
    }
  }
}

__global__ void gemm_128_64_kernel(const float* __restrict__ X, const void* __restrict__ W,
                                   float* __restrict__ Y, const Ctl* __restrict__ ctl,
                                   int M, int relu_x)
{
  __shared__ float Ws[128 * 64];
  __shared__ float Xs[32 * 128];
  const bool f32 = ctl->isfp32 != 0;
  const int tid = threadIdx.x;
  const int row0 = blockIdx.x * 32;

  for (int i = tid; i < 128 * 64; i += 256) Ws[i] = loadF(W, i, f32);
  for (int i = tid; i < 32 * 128; i += 256) {
    int r = i >> 7, k = i & 127;
    int gr = row0 + r;
    float v = (gr < M) ? X[(size_t)gr * 128 + k] : 0.0f;
    if (relu_x) v = fmaxf(v, 0.0f);
    Xs[i] = v;
  }
  __syncthreads();

  const int tx = tid & 31;
  const int ty = tid >> 5;
  float acc[4][2];
  #pragma unroll
  for (int i = 0; i < 4; ++i) { acc[i][0] = 0.f; acc[i][1] = 0.f; }
  for (int k = 0; k < 128; ++k) {
    float w0 = Ws[k * 64 + tx];
    float w1 = Ws[k * 64 + tx + 32];
    #pragma unroll
    for (int i = 0; i < 4; ++i) {
      float xv = Xs[(ty * 4 + i) * 128 + k];
      acc[i][0] += xv * w0;
      acc[i][1] += xv * w1;
    }
  }
  #pragma unroll
  for (int i = 0; i < 4; ++i) {
    int gr = row0 + ty * 4 + i;
    if (gr < M) {
      Y[(size_t)gr * 64 + tx]      = acc[i][0];
      Y[(size_t)gr * 64 + tx + 32] = acc[i][1];
    }
  }
}

__global__ void gemm_64_128_kernel(const float* __restrict__ X, const void* __restrict__ W,
                                   float* __restrict__ Y, const Ctl* __restrict__ ctl,
                                   int M, int relu_x)
{
  __shared__ float Ws[64 * 128];
  __shared__ float Xs[32 * 64];
  const bool f32 = ctl->isfp32 != 0;
  const int tid = threadIdx.x;
  const int row0 = blockIdx.x * 32;

  for (int i = tid; i < 64 * 128; i += 256) Ws[i] = loadF(W, i, f32);
  for (int i = tid; i < 32 * 64; i += 256) {
    int r = i >> 6, k = i & 63;
    int gr = row0 + r;
    float v = (gr < M) ? X[(size_t)gr * 64 + k] : 0.0f;
    if (relu_x) v = fmaxf(v, 0.0f);
    Xs[i] = v;
  }
  __syncthreads();

  const int tx = tid & 63;
  const int ty = tid >> 6;
  float acc[8][2];
  #pragma unroll
  for (int i = 0; i < 8; ++i) { acc[i][0] = 0.f; acc[i][1] = 0.f; }
  for (int k = 0; k < 64; ++k) {
    float w0 = Ws[k * 128 + tx];
    float w1 = Ws[k * 128 + tx + 64];
    #pragma unroll
    for (int i = 0; i < 8; ++i) {
      float xv = Xs[(ty * 8 + i) * 64 + k];
      acc[i][0] += xv * w0;
      acc[i][1] += xv * w1;
    }
  }
  #pragma unroll
  for (int i = 0; i < 8; ++i) {
    int gr = row0 + ty * 8 + i;
    if (gr < M) {
      Y[(size_t)gr * 128 + tx]      = acc[i][0];
      Y[(size_t)gr * 128 + tx + 64] = acc[i][1];
    }
  }
}

// ---------------- GCN aggregation: CSR gather (no atomics) ----------------

__global__ void agg_gather128_kernel(const float* __restrict__ hW, const int* __restrict__ rowstart,
                                     const int* __restrict__ csr, const float* __restrict__ dis,
                                     const void* __restrict__ b, const Ctl* __restrict__ ctl,
                                     float* __restrict__ agg, int M)
{
  const bool f32 = ctl->isfp32 != 0;
  int gid = blockIdx.x * 256 + threadIdx.x;
  int d = gid >> 6;
  int lane = gid & 63;
  if (d >= M) return;
  const float2* H = (const float2*)hW;
  float dd = dis[d];
  float2 h = H[(size_t)d * 64 + lane];
  float self = dd * dd;
  float ax = h.x * self + loadF(b, 2 * lane, f32);
  float ay = h.y * self + loadF(b, 2 * lane + 1, f32);
  int i0 = rowstart[d], i1 = rowstart[d + 1];
  for (int i = i0; i < i1; ++i) {
    int s = csr[i];
    float w = dd * dis[s];
    float2 v = H[(size_t)s * 64 + lane];
    ax += w * v.x;
    ay += w * v.y;
  }
  float2 o; o.x = ax; o.y = ay;
  ((float2*)agg)[(size_t)d * 64 + lane] = o;
}

__global__ void agg_gather64_kernel(const float* __restrict__ hW, const int* __restrict__ rowstart,
                                    const int* __restrict__ csr, const float* __restrict__ dis,
                                    const void* __restrict__ b, const Ctl* __restrict__ ctl,
                                    float* __restrict__ agg, int M)
{
  const bool f32 = ctl->isfp32 != 0;
  int gid = blockIdx.x * 256 + threadIdx.x;
  int d = gid >> 6;
  int lane = gid & 63;
  if (d >= M) return;
  float dd = dis[d];
  float a = hW[(size_t)d * 64 + lane] * (dd * dd) + loadF(b, lane, f32);
  int i0 = rowstart[d], i1 = rowstart[d + 1];
  for (int i = i0; i < i1; ++i) {
    int s = csr[i];
    a += (dd * dis[s]) * hW[(size_t)s * 64 + lane];
  }
  agg[(size_t)d * 64 + lane] = a;
}

// ---------------- TopK pooling ----------------

__global__ void score_kernel(const float* __restrict__ h, const void* __restrict__ pw,
                             const Ctl* __restrict__ ctl, float* __restrict__ score,
                             u64* __restrict__ keys)
{
  bool f32 = ctl->isfp32 != 0;
  int gid = blockIdx.x * 256 + threadIdx.x;
  int row = gid >> 6;
  int lane = gid & 63;
  if (row >= N_NODES) return;
  float a0 = fmaxf(h[(size_t)row * 128 + lane], 0.f) * loadF(pw, lane, f32);
  float a1 = fmaxf(h[(size_t)row * 128 + 64 + lane], 0.f) * loadF(pw, 64 + lane, f32);
  float s = a0 + a1;
  for (int off = 32; off; off >>= 1) s += __shfl_down(s, off);
  if (lane == 0) {
    float sc = tanhf(s * ctl->inv_norm);
    score[row] = sc;
    u32 u = __float_as_uint(sc);
    u = (u & 0x80000000u) ? ~u : (u | 0x80000000u);
    keys[row] = (((u64)u) << 32) | (u64)(0xFFFFFFFFu - (u32)row);
  }
}

// fused hist+pick: all blocks histogram into ctl->hist (device atomics);
// the last block to finish (done-counter) picks the digit and resets state.
__global__ void histpick_kernel(const u64* __restrict__ keys, Ctl* ctl, int shift, int nblocks) {
  __shared__ u32 lh[256];
  __shared__ int lastflag;
  const int tid = threadIdx.x;
  lh[tid] = 0;
  __syncthreads();
  u64 prefix = ctl->prefix;
  int i = blockIdx.x * 256 + tid;
  if (i < N_NODES) {
    u64 key = keys[i];
    bool match = (shift == 56) || ((key >> (shift + 8)) == (prefix >> (shift + 8)));
    if (match) atomicAdd(&lh[(u32)((key >> shift) & 0xFF)], 1u);
  }
  __syncthreads();
  u32 c = lh[tid];
  if (c) atomicAdd(&ctl->hist[tid], c);
  __syncthreads();
  if (tid == 0) {
    __threadfence();
    u32 old = atomicAdd(&ctl->done, 1u);
    lastflag = (old == (u32)(nblocks - 1));
  }
  __syncthreads();
  if (!lastflag) return;
  lh[tid] = atomicExch(&ctl->hist[tid], 0u);   // read + zero for next pass
  __syncthreads();
  if (tid == 0) {
    u32 kr = ctl->kremain;
    u32 cum = 0;
    int sel = 0;
    for (int v = 255; v >= 0; --v) {
      u32 cc = lh[v];
      if (cum + cc >= kr) { sel = v; break; }
      cum += cc;
    }
    ctl->prefix = prefix | (((u64)sel) << shift);
    ctl->kremain = kr - cum;
    ctl->done = 0u;
  }
}

__global__ void mark_kernel(const u64* __restrict__ keys, Ctl* ctl,
                            int* __restrict__ new_idx, int* __restrict__ kept)
{
  int i = blockIdx.x * 256 + threadIdx.x;
  if (i >= N_NODES) return;
  if (keys[i] >= ctl->prefix) {
    int pos = (int)atomicAdd(&ctl->cnt, 1u);
    new_idx[i] = pos;
    kept[pos] = i;
  } else {
    new_idx[i] = -1;
  }
}

__global__ void hp_kernel(const float* __restrict__ h, const int* __restrict__ kept,
                          const float* __restrict__ score, float* __restrict__ hp)
{
  int gid = blockIdx.x * 256 + threadIdx.x;
  int row = gid >> 6;
  int lane = gid & 63;
  if (row >= K_KEEP) return;
  int o = kept[row];
  float s = score[o];
  hp[(size_t)row * 128 + lane]      = fmaxf(h[(size_t)o * 128 + lane], 0.f) * s;
  hp[(size_t)row * 128 + 64 + lane] = fmaxf(h[(size_t)o * 128 + 64 + lane], 0.f) * s;
}

// ---------------- mean pool ----------------

__global__ void colsum_kernel(const float* __restrict__ h4, Ctl* ctl) {
  int c = threadIdx.x & 63;
  int rg = blockIdx.x * 4 + (threadIdx.x >> 6);
  float acc = 0.f;
  for (int r = rg; r < K_KEEP; r += 512) acc += h4[(size_t)r * 64 + c];
  atomicAdd(&ctl->colsum[c], acc);
}

__global__ void finalize_kernel(const Ctl* __restrict__ ctl, void* __restrict__ out) {
  int c = threadIdx.x; // 64
  float val = ctl->colsum[c] / (float)K_KEEP;
  if (ctl->isfp32) ((float*)out)[c] = val;
  else             ((__hip_bfloat16*)out)[c] = __float2bfloat16(val);
}

// ---------------- launch ----------------

extern "C" void kernel_launch(void* const* d_in, const int* in_sizes, int n_in,
                              void* d_out, int out_size, void* d_ws, size_t ws_size,
                              hipStream_t stream)
{
  const void* x  = d_in[0];
  const int*  ei = (const int*)d_in[1];
  const void* W1 = d_in[3];
  const void* b1 = d_in[4];
  const void* pw = d_in[5];
  const void* W2 = d_in[6];
  const void* b2 = d_in[7];
  const void* W3 = d_in[8];
  const void* b3 = d_in[9];
  const void* W4 = d_in[10];
  const void* b4 = d_in[11];

  const int* src = ei;
  const int* dst = ei + N_EDGES;

  float* F = (float*)d_ws;
  float* BufA      = F;                      // N x 128
  float* BufB      = F + 6400000;            // N x 128
  float* BufC      = F + 12800000;           // K x 128
  float* dis1      = F + 17920000;           // 50000
  float* dis2      = F + 17970000;           // 40000
  float* score     = F + 18010000;           // 50000
  u64*   keys      = (u64*)(F + 18060000);   // 50000 u64
  int*   new_idx   = (int*)(F + 18160000);   // 50000
  int*   kept      = (int*)(F + 18210000);   // 40000
  int*   cnt1      = (int*)(F + 18250000);   // 50000 (count -> cursor)
  int*   rowstart1 = (int*)(F + 18300000);   // 50001
  int*   cnt2      = (int*)(F + 18350004);   // 40000
  int*   rowstart2 = (int*)(F + 18390004);   // 40001
  int*   csr1      = (int*)(F + 18430008);   // 800000
  int*   csr2      = (int*)(F + 19230008);   // 800000
  Ctl*   ctl       = (Ctl*)(F + 20030008);   // ~1.3 KB
  int*   bsum      = (int*)(F + 20030500);   // 256
  int*   boff      = (int*)(F + 20030756);   // 256; total ~80.2 MB

  const int EB  = (N_EDGES + 255) / 256;     // 3125
  const int NB1 = (N_NODES + 255) / 256;     // 196
  const int NB2 = (K_KEEP + 255) / 256;      // 157

  init_kernel<<<NB1, 256, 0, stream>>>(cnt1, cnt2, ctl);
  detect_kernel<<<1, 256, 0, stream>>>(x, ctl);
  norm_kernel<<<1, 64, 0, stream>>>(pw, ctl);

  // CSR for graph 1
  csr_count1_kernel<<<EB, 256, 0, stream>>>(dst, cnt1);
  block_reduce_kernel<<<NB1, 256, 0, stream>>>(cnt1, bsum, N_NODES);
  scan_bsum_kernel<<<1, 256, 0, stream>>>(bsum, boff, NB1, &rowstart1[N_NODES]);
  block_scanout_kernel<<<NB1, 256, 0, stream>>>(cnt1, boff, rowstart1, dis1, N_NODES);
  csr_fill1_kernel<<<EB, 256, 0, stream>>>(src, dst, cnt1, csr1);

  // conv1: h = relu(gcn(x, W1, b1))  [relu folded into consumers]
  gemm_in_kernel<<<(N_NODES + 31) / 32, 256, 0, stream>>>(x, W1, BufA, ctl);
  agg_gather128_kernel<<<(N_NODES + 3) / 4, 256, 0, stream>>>(BufA, rowstart1, csr1, dis1, b1, ctl, BufB, N_NODES);

  // pooling
  score_kernel<<<(N_NODES + 3) / 4, 256, 0, stream>>>(BufB, pw, ctl, score, keys);
  for (int p = 0; p < 8; ++p)
    histpick_kernel<<<NB1, 256, 0, stream>>>(keys, ctl, 56 - 8 * p, NB1);
  mark_kernel<<<NB1, 256, 0, stream>>>(keys, ctl, new_idx, kept);
  hp_kernel<<<(K_KEEP + 3) / 4, 256, 0, stream>>>(BufB, kept, score, BufC);

  // CSR for pooled graph
  csr_count2_kernel<<<EB, 256, 0, stream>>>(src, dst, new_idx, cnt2);
  block_reduce_kernel<<<NB2, 256, 0, stream>>>(cnt2, bsum, K_KEEP);
  scan_bsum_kernel<<<1, 256, 0, stream>>>(bsum, boff, NB2, &rowstart2[K_KEEP]);
  block_scanout_kernel<<<NB2, 256, 0, stream>>>(cnt2, boff, rowstart2, dis2, K_KEEP);
  csr_fill2_kernel<<<EB, 256, 0, stream>>>(src, dst, new_idx, cnt2, csr2);

  // conv2
  gemm_128_64_kernel<<<(K_KEEP + 31) / 32, 256, 0, stream>>>(BufC, W2, BufA, ctl, K_KEEP, 0);
  agg_gather64_kernel<<<(K_KEEP + 3) / 4, 256, 0, stream>>>(BufA, rowstart2, csr2, dis2, b2, ctl, BufC, K_KEEP);

  // conv3
  gemm_64_128_kernel<<<(K_KEEP + 31) / 32, 256, 0, stream>>>(BufC, W3, BufA, ctl, K_KEEP, 1);
  agg_gather128_kernel<<<(K_KEEP + 3) / 4, 256, 0, stream>>>(BufA, rowstart2, csr2, dis2, b3, ctl, BufB, K_KEEP);

  // conv4
  gemm_128_64_kernel<<<(K_KEEP + 31) / 32, 256, 0, stream>>>(BufB, W4, BufA, ctl, K_KEEP, 1);
  agg_gather64_kernel<<<(K_KEEP + 3) / 4, 256, 0, stream>>>(BufA, rowstart2, csr2, dis2, b4, ctl, BufC, K_KEEP);

  // mean
  colsum_kernel<<<128, 256, 0, stream>>>(BufC, ctl);
  finalize_kernel<<<1, 64, 0, stream>>>(ctl, d_out);
}

// Round 6
// 769.068 us; speedup vs baseline: 1.6686x; 1.0944x over previous
//
#include <hip/hip_runtime.h>
#include <hip/hip_bf16.h>
#include <stdint.h>

#define N_NODES 50000
#define N_EDGES 800000
#define K_KEEP  40000

typedef unsigned long long u64;
typedef unsigned int u32;
typedef __hip_bfloat16 bf16;
typedef __hip_bfloat162 bf16x2;

struct Ctl {
  u64 prefix;
  u32 kremain;
  u32 cnt;
  float inv_norm;
  u32 isfp32;
  u32 done;
  u32 pad;
  u32 hist[256];
  float colsum[64];
};

__device__ __forceinline__ float bf2f(bf16 v) { return __bfloat162float(v); }
__device__ __forceinline__ float loadF(const void* p, size_t i, bool f32) {
  return f32 ? ((const float*)p)[i] : bf2f(((const bf16*)p)[i]);
}

// ---------------- init (+parallel dtype detect) ----------------

// blocks 0..63 also count bf16 exp==0xFF patterns in x halfwords (fp32 data
// read as halfwords shows ~1/256 such patterns; true bf16 N(0,1) shows none).
// Per-block plain store to detcnt[] (no zero/add race); norm_kernel sums.
__global__ void init_kernel(const unsigned short* __restrict__ x16,
                            int* __restrict__ cnt1, int* __restrict__ cnt2,
                            int* __restrict__ detcnt, Ctl* ctl) {
  __shared__ u32 dsh[256];
  int i = blockIdx.x * 256 + threadIdx.x;
  if (i < N_NODES) cnt1[i] = 0;
  if (i < K_KEEP)  cnt2[i] = 0;
  if (blockIdx.x == 0) {
    ctl->hist[threadIdx.x] = 0u;
    if (threadIdx.x < 64) ctl->colsum[threadIdx.x] = 0.0f;
    if (threadIdx.x == 0) { ctl->prefix = 0ull; ctl->kremain = K_KEEP; ctl->cnt = 0u; ctl->done = 0u; }
  }
  if (blockIdx.x < 64) {
    int base = blockIdx.x * 2048;
    u32 c = 0;
    for (int j = threadIdx.x; j < 2048; j += 256) {
      u32 h = x16[base + j];
      if ((h & 0x7F80u) == 0x7F80u) c++;
    }
    dsh[threadIdx.x] = c;
    __syncthreads();
    for (int s = 128; s > 0; s >>= 1) {
      if (threadIdx.x < s) dsh[threadIdx.x] += dsh[threadIdx.x + s];
      __syncthreads();
    }
    if (threadIdx.x == 0) detcnt[blockIdx.x] = (int)dsh[0];
  }
}

__global__ void norm_kernel(const void* __restrict__ pw, const int* __restrict__ detcnt, Ctl* ctl) {
  int lane = threadIdx.x;   // 64
  int dc = detcnt[lane];
  for (int off = 32; off; off >>= 1) dc += __shfl_down(dc, off);
  dc = __shfl(dc, 0);
  bool f32 = (dc >= 16);
  float v0 = loadF(pw, lane, f32);
  float v1 = loadF(pw, 64 + lane, f32);
  float s = v0 * v0 + v1 * v1;
  for (int off = 32; off; off >>= 1) s += __shfl_down(s, off);
  if (lane == 0) {
    ctl->inv_norm = 1.0f / sqrtf(s);
    ctl->isfp32 = f32 ? 1u : 0u;
  }
}

// ---------------- CSR build ----------------

__global__ void csr_count1_kernel(const int* __restrict__ dst, int* __restrict__ cnt) {
  int e = blockIdx.x * 256 + threadIdx.x;
  if (e < N_EDGES) atomicAdd(&cnt[dst[e]], 1);
}

__global__ void block_reduce_kernel(const int* __restrict__ cnt, int* __restrict__ bsum, int n) {
  __shared__ int sh[256];
  int i = blockIdx.x * 256 + threadIdx.x;
  sh[threadIdx.x] = (i < n) ? cnt[i] : 0;
  __syncthreads();
  for (int s = 128; s > 0; s >>= 1) {
    if (threadIdx.x < s) sh[threadIdx.x] += sh[threadIdx.x + s];
    __syncthreads();
  }
  if (threadIdx.x == 0) bsum[blockIdx.x] = sh[0];
}

__global__ void scan_bsum_kernel(const int* __restrict__ bsum, int* __restrict__ boff,
                                 int nb, int* __restrict__ rowstart_n) {
  __shared__ int sh[256];
  int tid = threadIdx.x;
  int v = (tid < nb) ? bsum[tid] : 0;
  sh[tid] = v;
  __syncthreads();
  for (int off = 1; off < 256; off <<= 1) {
    int t = (tid >= off) ? sh[tid - off] : 0;
    __syncthreads();
    sh[tid] += t;
    __syncthreads();
  }
  if (tid < nb) boff[tid] = sh[tid] - v;
  if (tid == 255) *rowstart_n = sh[255];
}

__global__ void block_scanout_kernel(int* __restrict__ cnt, const int* __restrict__ boff,
                                     int* __restrict__ rowstart, float* __restrict__ dis, int n) {
  __shared__ int sh[256];
  int tid = threadIdx.x;
  int i = blockIdx.x * 256 + tid;
  int c = (i < n) ? cnt[i] : 0;
  sh[tid] = c;
  __syncthreads();
  for (int off = 1; off < 256; off <<= 1) {
    int t = (tid >= off) ? sh[tid - off] : 0;
    __syncthreads();
    sh[tid] += t;
    __syncthreads();
  }
  if (i < n) {
    int pos = boff[blockIdx.x] + sh[tid] - c;
    rowstart[i] = pos;
    cnt[i] = pos;                              // fill cursor
    dis[i] = rsqrtf(1.0f + (float)c);
  }
}

__global__ void csr_fill1_kernel(const int* __restrict__ src, const int* __restrict__ dst,
                                 int* __restrict__ cur, int* __restrict__ csr) {
  int e = blockIdx.x * 256 + threadIdx.x;
  if (e >= N_EDGES) return;
  int pos = atomicAdd(&cur[dst[e]], 1);
  csr[pos] = src[e];
}

__global__ void csr_count2_kernel(const int* __restrict__ src, const int* __restrict__ dst,
                                  const int* __restrict__ new_idx, int* __restrict__ cnt) {
  int e = blockIdx.x * 256 + threadIdx.x;
  if (e >= N_EDGES) return;
  int s = new_idx[src[e]];
  int d = new_idx[dst[e]];
  if (s >= 0 && d >= 0) atomicAdd(&cnt[d], 1);
}

__global__ void csr_fill2_kernel(const int* __restrict__ src, const int* __restrict__ dst,
                                 const int* __restrict__ new_idx, int* __restrict__ cur,
                                 int* __restrict__ csr) {
  int e = blockIdx.x * 256 + threadIdx.x;
  if (e >= N_EDGES) return;
  int s = new_idx[src[e]];
  int d = new_idx[dst[e]];
  if (s < 0 || d < 0) return;
  int pos = atomicAdd(&cur[d], 1);
  csr[pos] = s;
}

// ---------------- GEMMs (fp32 accumulate, bf16 out) ----------------

// conv1: Y[N,128] = X[N,64] @ W[64,128]; X dtype via flag
__global__ void gemm_in_kernel(const void* __restrict__ Xv, const void* __restrict__ W,
                               bf16* __restrict__ Y, const Ctl* __restrict__ ctl)
{
  __shared__ float Ws[64 * 128];
  __shared__ float Xs[32 * 64];
  const bool f32 = ctl->isfp32 != 0;
  const int tid = threadIdx.x;
  const int row0 = blockIdx.x * 32;

  for (int i = tid; i < 64 * 128; i += 256) Ws[i] = loadF(W, i, f32);
  for (int i = tid; i < 32 * 64; i += 256) {
    int r = i >> 6, k = i & 63;
    int gr = row0 + r;
    Xs[i] = (gr < N_NODES) ? loadF(Xv, (size_t)gr * 64 + k, f32) : 0.0f;
  }
  __syncthreads();

  const int tx = tid & 63;
  const int ty = tid >> 6;
  float acc[8][2];
  #pragma unroll
  for (int i = 0; i < 8; ++i) { acc[i][0] = 0.f; acc[i][1] = 0.f; }
  for (int k = 0; k < 64; ++k) {
    float w0 = Ws[k * 128 + tx];
    float w1 = Ws[k * 128 + tx + 64];
    #pragma unroll
    for (int i = 0; i < 8; ++i) {
      float xv = Xs[(ty * 8 + i) * 64 + k];
      acc[i][0] += xv * w0;
      acc[i][1] += xv * w1;
    }
  }
  #pragma unroll
  for (int i = 0; i < 8; ++i) {
    int gr = row0 + ty * 8 + i;
    if (gr < N_NODES) {
      Y[(size_t)gr * 128 + tx]      = __float2bfloat16(acc[i][0]);
      Y[(size_t)gr * 128 + tx + 64] = __float2bfloat16(acc[i][1]);
    }
  }
}

// Y[M,64] = (relu?)X[M,128] @ W[128,64]; X bf16
__global__ void gemm_128_64_kernel(const bf16* __restrict__ X, const void* __restrict__ W,
                                   bf16* __restrict__ Y, const Ctl* __restrict__ ctl,
                                   int M, int relu_x)
{
  __shared__ float Ws[128 * 64];
  __shared__ float Xs[32 * 128];
  const bool f32 = ctl->isfp32 != 0;
  const int tid = threadIdx.x;
  const int row0 = blockIdx.x * 32;

  for (int i = tid; i < 128 * 64; i += 256) Ws[i] = loadF(W, i, f32);
  const bf16x2* X2 = (const bf16x2*)X;
  for (int p = tid; p < 32 * 64; p += 256) {   // pairs: 64/row
    int r = p >> 6, kp = p & 63;
    int gr = row0 + r;
    float vx = 0.f, vy = 0.f;
    if (gr < M) {
      bf16x2 v = X2[(size_t)gr * 64 + kp];
      vx = bf2f(v.x); vy = bf2f(v.y);
      if (relu_x) { vx = fmaxf(vx, 0.f); vy = fmaxf(vy, 0.f); }
    }
    Xs[r * 128 + 2 * kp]     = vx;
    Xs[r * 128 + 2 * kp + 1] = vy;
  }
  __syncthreads();

  const int tx = tid & 31;
  const int ty = tid >> 5;
  float acc[4][2];
  #pragma unroll
  for (int i = 0; i < 4; ++i) { acc[i][0] = 0.f; acc[i][1] = 0.f; }
  for (int k = 0; k < 128; ++k) {
    float w0 = Ws[k * 64 + tx];
    float w1 = Ws[k * 64 + tx + 32];
    #pragma unroll
    for (int i = 0; i < 4; ++i) {
      float xv = Xs[(ty * 4 + i) * 128 + k];
      acc[i][0] += xv * w0;
      acc[i][1] += xv * w1;
    }
  }
  #pragma unroll
  for (int i = 0; i < 4; ++i) {
    int gr = row0 + ty * 4 + i;
    if (gr < M) {
      Y[(size_t)gr * 64 + tx]      = __float2bfloat16(acc[i][0]);
      Y[(size_t)gr * 64 + tx + 32] = __float2bfloat16(acc[i][1]);
    }
  }
}

// Y[M,128] = (relu?)X[M,64] @ W[64,128]; X bf16
__global__ void gemm_64_128_kernel(const bf16* __restrict__ X, const void* __restrict__ W,
                                   bf16* __restrict__ Y, const Ctl* __restrict__ ctl,
                                   int M, int relu_x)
{
  __shared__ float Ws[64 * 128];
  __shared__ float Xs[32 * 64];
  const bool f32 = ctl->isfp32 != 0;
  const int tid = threadIdx.x;
  const int row0 = blockIdx.x * 32;

  for (int i = tid; i < 64 * 128; i += 256) Ws[i] = loadF(W, i, f32);
  const bf16x2* X2 = (const bf16x2*)X;
  for (int p = tid; p < 32 * 32; p += 256) {   // pairs: 32/row
    int r = p >> 5, kp = p & 31;
    int gr = row0 + r;
    float vx = 0.f, vy = 0.f;
    if (gr < M) {
      bf16x2 v = X2[(size_t)gr * 32 + kp];
      vx = bf2f(v.x); vy = bf2f(v.y);
      if (relu_x) { vx = fmaxf(vx, 0.f); vy = fmaxf(vy, 0.f); }
    }
    Xs[r * 64 + 2 * kp]     = vx;
    Xs[r * 64 + 2 * kp + 1] = vy;
  }
  __syncthreads();

  const int tx = tid & 63;
  const int ty = tid >> 6;
  float acc[8][2];
  #pragma unroll
  for (int i = 0; i < 8; ++i) { acc[i][0] = 0.f; acc[i][1] = 0.f; }
  for (int k = 0; k < 64; ++k) {
    float w0 = Ws[k * 128 + tx];
    float w1 = Ws[k * 128 + tx + 64];
    #pragma unroll
    for (int i = 0; i < 8; ++i) {
      float xv = Xs[(ty * 8 + i) * 64 + k];
      acc[i][0] += xv * w0;
      acc[i][1] += xv * w1;
    }
  }
  #pragma unroll
  for (int i = 0; i < 8; ++i) {
    int gr = row0 + ty * 8 + i;
    if (gr < M) {
      Y[(size_t)gr * 128 + tx]      = __float2bfloat16(acc[i][0]);
      Y[(size_t)gr * 128 + tx + 64] = __float2bfloat16(acc[i][1]);
    }
  }
}

// ---------------- GCN aggregation: CSR gather, bf16 rows ----------------

// wave per dst node, lane = channel pair; optional fused pooling score
__global__ void agg_gather128_kernel(const bf16* __restrict__ hW, const int* __restrict__ rowstart,
                                     const int* __restrict__ csr, const float* __restrict__ dis,
                                     const void* __restrict__ b, const void* __restrict__ pw,
                                     const Ctl* __restrict__ ctl, bf16* __restrict__ agg,
                                     float* __restrict__ score, u64* __restrict__ keys,
                                     int M, int do_score)
{
  const bool f32 = ctl->isfp32 != 0;
  int gid = blockIdx.x * 256 + threadIdx.x;
  int d = gid >> 6;
  int lane = gid & 63;
  if (d >= M) return;
  const bf16x2* H = (const bf16x2*)hW;
  float dd = dis[d];
  bf16x2 h = H[(size_t)d * 64 + lane];
  float self = dd * dd;
  float ax = bf2f(h.x) * self + loadF(b, 2 * lane, f32);
  float ay = bf2f(h.y) * self + loadF(b, 2 * lane + 1, f32);
  int i0 = rowstart[d], i1 = rowstart[d + 1];
  for (int i = i0; i < i1; ++i) {
    int s = csr[i];
    float w = dd * dis[s];
    bf16x2 v = H[(size_t)s * 64 + lane];
    ax += w * bf2f(v.x);
    ay += w * bf2f(v.y);
  }
  bf16x2 o; o.x = __float2bfloat16(ax); o.y = __float2bfloat16(ay);
  ((bf16x2*)agg)[(size_t)d * 64 + lane] = o;
  if (do_score) {
    float s = fmaxf(ax, 0.f) * loadF(pw, 2 * lane, f32)
            + fmaxf(ay, 0.f) * loadF(pw, 2 * lane + 1, f32);
    for (int off = 32; off; off >>= 1) s += __shfl_down(s, off);
    if (lane == 0) {
      float sc = tanhf(s * ctl->inv_norm);
      score[d] = sc;
      u32 u = __float_as_uint(sc);
      u = (u & 0x80000000u) ? ~u : (u | 0x80000000u);
      keys[d] = (((u64)u) << 16) | (u64)(0xFFFFu - (u32)d);   // 48-bit key, N<2^16
    }
  }
}

// wave per dst node, lane = channel (64 ch), bf16 out
__global__ void agg_gather64_kernel(const bf16* __restrict__ hW, const int* __restrict__ rowstart,
                                    const int* __restrict__ csr, const float* __restrict__ dis,
                                    const void* __restrict__ b, const Ctl* __restrict__ ctl,
                                    bf16* __restrict__ agg, int M)
{
  const bool f32 = ctl->isfp32 != 0;
  int gid = blockIdx.x * 256 + threadIdx.x;
  int d = gid >> 6;
  int lane = gid & 63;
  if (d >= M) return;
  float dd = dis[d];
  float a = bf2f(hW[(size_t)d * 64 + lane]) * (dd * dd) + loadF(b, lane, f32);
  int i0 = rowstart[d], i1 = rowstart[d + 1];
  for (int i = i0; i < i1; ++i) {
    int s = csr[i];
    a += (dd * dis[s]) * bf2f(hW[(size_t)s * 64 + lane]);
  }
  agg[(size_t)d * 64 + lane] = __float2bfloat16(a);
}

// conv4: gather + mean-pool reduction fused; no row store
__global__ void agg_gather64_final_kernel(const bf16* __restrict__ hW, const int* __restrict__ rowstart,
                                          const int* __restrict__ csr, const float* __restrict__ dis,
                                          const void* __restrict__ b, Ctl* ctl, int M)
{
  __shared__ float cs[64];
  const bool f32 = ctl->isfp32 != 0;
  int tid = threadIdx.x;
  if (tid < 64) cs[tid] = 0.f;
  __syncthreads();
  int gid = blockIdx.x * 256 + tid;
  int d = gid >> 6;
  int lane = gid & 63;
  if (d < M) {
    float dd = dis[d];
    float a = bf2f(hW[(size_t)d * 64 + lane]) * (dd * dd) + loadF(b, lane, f32);
    int i0 = rowstart[d], i1 = rowstart[d + 1];
    for (int i = i0; i < i1; ++i) {
      int s = csr[i];
      a += (dd * dis[s]) * bf2f(hW[(size_t)s * 64 + lane]);
    }
    atomicAdd(&cs[lane], a);
  }
  __syncthreads();
  if (tid < 64) atomicAdd(&ctl->colsum[tid], cs[tid]);
}

// ---------------- TopK select ----------------

// fused hist+pick (R5-proven last-block pattern); 6 passes over 48-bit keys
__global__ void histpick_kernel(const u64* __restrict__ keys, Ctl* ctl, int shift, int nblocks) {
  __shared__ u32 lh[256];
  __shared__ int lastflag;
  const int tid = threadIdx.x;
  lh[tid] = 0;
  __syncthreads();
  u64 prefix = ctl->prefix;
  int i = blockIdx.x * 256 + tid;
  if (i < N_NODES) {
    u64 key = keys[i];
    if ((key >> (shift + 8)) == (prefix >> (shift + 8)))
      atomicAdd(&lh[(u32)((key >> shift) & 0xFF)], 1u);
  }
  __syncthreads();
  u32 c = lh[tid];
  if (c) atomicAdd(&ctl->hist[tid], c);
  __syncthreads();
  if (tid == 0) {
    __threadfence();
    u32 old = atomicAdd(&ctl->done, 1u);
    lastflag = (old == (u32)(nblocks - 1));
  }
  __syncthreads();
  if (!lastflag) return;
  lh[tid] = atomicExch(&ctl->hist[tid], 0u);
  __syncthreads();
  if (tid == 0) {
    u32 kr = ctl->kremain;
    u32 cum = 0;
    int sel = 0;
    for (int v = 255; v >= 0; --v) {
      u32 cc = lh[v];
      if (cum + cc >= kr) { sel = v; break; }
      cum += cc;
    }
    ctl->prefix = prefix | (((u64)sel) << shift);
    ctl->kremain = kr - cum;
    ctl->done = 0u;
  }
}

__global__ void mark_kernel(const u64* __restrict__ keys, Ctl* ctl,
                            int* __restrict__ new_idx, int* __restrict__ kept)
{
  int i = blockIdx.x * 256 + threadIdx.x;
  if (i >= N_NODES) return;
  if (keys[i] >= ctl->prefix) {
    int pos = (int)atomicAdd(&ctl->cnt, 1u);
    new_idx[i] = pos;
    kept[pos] = i;
  } else {
    new_idx[i] = -1;
  }
}

// hp[pos] = relu(h[orig]) * score[orig]; bf16 in/out, wave per row
__global__ void hp_kernel(const bf16* __restrict__ h, const int* __restrict__ kept,
                          const float* __restrict__ score, bf16* __restrict__ hp)
{
  int gid = blockIdx.x * 256 + threadIdx.x;
  int row = gid >> 6;
  int lane = gid & 63;
  if (row >= K_KEEP) return;
  int o = kept[row];
  float s = score[o];
  bf16x2 v = ((const bf16x2*)h)[(size_t)o * 64 + lane];
  bf16x2 w;
  w.x = __float2bfloat16(fmaxf(bf2f(v.x), 0.f) * s);
  w.y = __float2bfloat16(fmaxf(bf2f(v.y), 0.f) * s);
  ((bf16x2*)hp)[(size_t)row * 64 + lane] = w;
}

__global__ void finalize_kernel(const Ctl* __restrict__ ctl, void* __restrict__ out) {
  int c = threadIdx.x; // 64
  float val = ctl->colsum[c] / (float)K_KEEP;
  if (ctl->isfp32) ((float*)out)[c] = val;
  else             ((bf16*)out)[c] = __float2bfloat16(val);
}

// ---------------- launch ----------------

extern "C" void kernel_launch(void* const* d_in, const int* in_sizes, int n_in,
                              void* d_out, int out_size, void* d_ws, size_t ws_size,
                              hipStream_t stream)
{
  const void* x  = d_in[0];
  const int*  ei = (const int*)d_in[1];
  const void* W1 = d_in[3];
  const void* b1 = d_in[4];
  const void* pw = d_in[5];
  const void* W2 = d_in[6];
  const void* b2 = d_in[7];
  const void* W3 = d_in[8];
  const void* b3 = d_in[9];
  const void* W4 = d_in[10];
  const void* b4 = d_in[11];

  const int* src = ei;
  const int* dst = ei + N_EDGES;

  float* F = (float*)d_ws;
  bf16*  A16       = (bf16*)F;               // N x 128 bf16 (3.2M floats)
  bf16*  B16       = (bf16*)(F + 3200000);   // N x 128 bf16
  bf16*  C16       = (bf16*)(F + 6400000);   // K x 128 bf16 (2.56M floats)
  float* dis1      = F + 9000000;            // 50000
  float* dis2      = F + 9050000;            // 40000
  float* score     = F + 9100000;            // 50000
  u64*   keys      = (u64*)(F + 9150000);    // 50000 u64 (8B-aligned byte off)
  int*   new_idx   = (int*)(F + 9250000);    // 50000
  int*   kept      = (int*)(F + 9300000);    // 40000
  int*   cnt1      = (int*)(F + 9350000);    // 50000
  int*   rowstart1 = (int*)(F + 9400000);    // 50001
  int*   cnt2      = (int*)(F + 9450004);    // 40000
  int*   rowstart2 = (int*)(F + 9490004);    // 40001
  int*   csr1      = (int*)(F + 9530008);    // 800000
  int*   csr2      = (int*)(F + 10330008);   // 800000
  Ctl*   ctl       = (Ctl*)(F + 11130008);   // ~1.3 KB
  int*   bsum      = (int*)(F + 11131000);   // 256
  int*   boff      = (int*)(F + 11131256);   // 256
  int*   detcnt    = (int*)(F + 11131512);   // 64  (total ~44.5 MB)

  const int EB  = (N_EDGES + 255) / 256;     // 3125
  const int NB1 = (N_NODES + 255) / 256;     // 196
  const int NB2 = (K_KEEP + 255) / 256;      // 157

  init_kernel<<<NB1, 256, 0, stream>>>((const unsigned short*)x, cnt1, cnt2, detcnt, ctl);
  norm_kernel<<<1, 64, 0, stream>>>(pw, detcnt, ctl);

  // CSR for graph 1
  csr_count1_kernel<<<EB, 256, 0, stream>>>(dst, cnt1);
  block_reduce_kernel<<<NB1, 256, 0, stream>>>(cnt1, bsum, N_NODES);
  scan_bsum_kernel<<<1, 256, 0, stream>>>(bsum, boff, NB1, &rowstart1[N_NODES]);
  block_scanout_kernel<<<NB1, 256, 0, stream>>>(cnt1, boff, rowstart1, dis1, N_NODES);
  csr_fill1_kernel<<<EB, 256, 0, stream>>>(src, dst, cnt1, csr1);

  // conv1: h = gcn(x, W1, b1); relu folded into consumers; score fused
  gemm_in_kernel<<<(N_NODES + 31) / 32, 256, 0, stream>>>(x, W1, A16, ctl);
  agg_gather128_kernel<<<(N_NODES + 3) / 4, 256, 0, stream>>>(A16, rowstart1, csr1, dis1, b1, pw, ctl, B16, score, keys, N_NODES, 1);

  // top-K select (6 x 8-bit radix over 48-bit keys)
  for (int p = 0; p < 6; ++p)
    histpick_kernel<<<NB1, 256, 0, stream>>>(keys, ctl, 40 - 8 * p, NB1);
  mark_kernel<<<NB1, 256, 0, stream>>>(keys, ctl, new_idx, kept);
  hp_kernel<<<(K_KEEP + 3) / 4, 256, 0, stream>>>(B16, kept, score, C16);

  // CSR for pooled graph
  csr_count2_kernel<<<EB, 256, 0, stream>>>(src, dst, new_idx, cnt2);
  block_reduce_kernel<<<NB2, 256, 0, stream>>>(cnt2, bsum, K_KEEP);
  scan_bsum_kernel<<<1, 256, 0, stream>>>(bsum, boff, NB2, &rowstart2[K_KEEP]);
  block_scanout_kernel<<<NB2, 256, 0, stream>>>(cnt2, boff, rowstart2, dis2, K_KEEP);
  csr_fill2_kernel<<<EB, 256, 0, stream>>>(src, dst, new_idx, cnt2, csr2);

  // conv2
  gemm_128_64_kernel<<<K_KEEP / 32, 256, 0, stream>>>(C16, W2, A16, ctl, K_KEEP, 0);
  agg_gather64_kernel<<<K_KEEP / 4, 256, 0, stream>>>(A16, rowstart2, csr2, dis2, b2, ctl, B16, K_KEEP);

  // conv3
  gemm_64_128_kernel<<<K_KEEP / 32, 256, 0, stream>>>(B16, W3, A16, ctl, K_KEEP, 1);
  agg_gather128_kernel<<<K_KEEP / 4, 256, 0, stream>>>(A16, rowstart2, csr2, dis2, b3, pw, ctl, C16, score, keys, K_KEEP, 0);

  // conv4 (+fused mean pool)
  gemm_128_64_kernel<<<K_KEEP / 32, 256, 0, stream>>>(C16, W4, A16, ctl, K_KEEP, 1);
  agg_gather64_final_kernel<<<K_KEEP / 4, 256, 0, stream>>>(A16, rowstart2, csr2, dis2, b4, ctl, K_KEEP);

  finalize_kernel<<<1, 64, 0, stream>>>(ctl, d_out);
}

// Round 7
// 580.339 us; speedup vs baseline: 2.2112x; 1.3252x over previous
//
#include <hip/hip_runtime.h>
#include <hip/hip_bf16.h>
#include <stdint.h>

#define N_NODES 50000
#define N_EDGES 800000
#define K_KEEP  40000

typedef unsigned long long u64;
typedef unsigned int u32;
typedef __hip_bfloat16 bf16;
typedef __hip_bfloat162 bf16x2;

struct Ctl {
  u64 prefix;
  u32 kremain;
  u32 cnt;
  float inv_norm;
  u32 isfp32;
  u32 done;
  u32 pad;
  u32 hist[256];
};

__device__ __forceinline__ float bf2f(bf16 v) { return __bfloat162float(v); }
__device__ __forceinline__ float loadF(const void* p, size_t i, bool f32) {
  return f32 ? ((const float*)p)[i] : bf2f(((const bf16*)p)[i]);
}

// ---------------- init (+parallel dtype detect, proven R5/R6) ----------------

__global__ void init_kernel(const unsigned short* __restrict__ x16,
                            int* __restrict__ cnt1, int* __restrict__ cnt2,
                            int* __restrict__ detcnt, Ctl* ctl) {
  __shared__ u32 dsh[256];
  int i = blockIdx.x * 256 + threadIdx.x;
  if (i < N_NODES) cnt1[i] = 0;
  if (i < K_KEEP)  cnt2[i] = 0;
  if (blockIdx.x == 0) {
    ctl->hist[threadIdx.x] = 0u;
    if (threadIdx.x == 0) { ctl->prefix = 0ull; ctl->kremain = K_KEEP; ctl->cnt = 0u; ctl->done = 0u; }
  }
  if (blockIdx.x < 64) {
    int base = blockIdx.x * 2048;
    u32 c = 0;
    for (int j = threadIdx.x; j < 2048; j += 256) {
      u32 h = x16[base + j];
      if ((h & 0x7F80u) == 0x7F80u) c++;
    }
    dsh[threadIdx.x] = c;
    __syncthreads();
    for (int s = 128; s > 0; s >>= 1) {
      if (threadIdx.x < s) dsh[threadIdx.x] += dsh[threadIdx.x + s];
      __syncthreads();
    }
    if (threadIdx.x == 0) detcnt[blockIdx.x] = (int)dsh[0];
  }
}

__global__ void norm_kernel(const void* __restrict__ pw, const int* __restrict__ detcnt, Ctl* ctl) {
  int lane = threadIdx.x;   // 64
  int dc = detcnt[lane];
  for (int off = 32; off; off >>= 1) dc += __shfl_down(dc, off);
  dc = __shfl(dc, 0);
  bool f32 = (dc >= 16);
  float v0 = loadF(pw, lane, f32);
  float v1 = loadF(pw, 64 + lane, f32);
  float s = v0 * v0 + v1 * v1;
  for (int off = 32; off; off >>= 1) s += __shfl_down(s, off);
  if (lane == 0) {
    ctl->inv_norm = 1.0f / sqrtf(s);
    ctl->isfp32 = f32 ? 1u : 0u;
  }
}

// ---------------- CSR build ----------------

__global__ void csr_count1_kernel(const int* __restrict__ dst, int* __restrict__ cnt) {
  int e = blockIdx.x * 256 + threadIdx.x;
  if (e < N_EDGES) atomicAdd(&cnt[dst[e]], 1);
}

__global__ void block_reduce_kernel(const int* __restrict__ cnt, int* __restrict__ bsum, int n) {
  __shared__ int sh[256];
  int i = blockIdx.x * 256 + threadIdx.x;
  sh[threadIdx.x] = (i < n) ? cnt[i] : 0;
  __syncthreads();
  for (int s = 128; s > 0; s >>= 1) {
    if (threadIdx.x < s) sh[threadIdx.x] += sh[threadIdx.x + s];
    __syncthreads();
  }
  if (threadIdx.x == 0) bsum[blockIdx.x] = sh[0];
}

__global__ void scan_bsum_kernel(const int* __restrict__ bsum, int* __restrict__ boff,
                                 int nb, int* __restrict__ rowstart_n) {
  __shared__ int sh[256];
  int tid = threadIdx.x;
  int v = (tid < nb) ? bsum[tid] : 0;
  sh[tid] = v;
  __syncthreads();
  for (int off = 1; off < 256; off <<= 1) {
    int t = (tid >= off) ? sh[tid - off] : 0;
    __syncthreads();
    sh[tid] += t;
    __syncthreads();
  }
  if (tid < nb) boff[tid] = sh[tid] - v;
  if (tid == 255) *rowstart_n = sh[255];
}

__global__ void block_scanout_kernel(int* __restrict__ cnt, const int* __restrict__ boff,
                                     int* __restrict__ rowstart, float* __restrict__ dis, int n) {
  __shared__ int sh[256];
  int tid = threadIdx.x;
  int i = blockIdx.x * 256 + tid;
  int c = (i < n) ? cnt[i] : 0;
  sh[tid] = c;
  __syncthreads();
  for (int off = 1; off < 256; off <<= 1) {
    int t = (tid >= off) ? sh[tid - off] : 0;
    __syncthreads();
    sh[tid] += t;
    __syncthreads();
  }
  if (i < n) {
    int pos = boff[blockIdx.x] + sh[tid] - c;
    rowstart[i] = pos;
    cnt[i] = pos;                              // fill cursor
    dis[i] = rsqrtf(1.0f + (float)c);
  }
}

__global__ void csr_fill1_kernel(const int* __restrict__ src, const int* __restrict__ dst,
                                 int* __restrict__ cur, int* __restrict__ csr) {
  int e = blockIdx.x * 256 + threadIdx.x;
  if (e >= N_EDGES) return;
  int pos = atomicAdd(&cur[dst[e]], 1);
  csr[pos] = src[e];
}

__global__ void csr_count2_kernel(const int* __restrict__ src, const int* __restrict__ dst,
                                  const int* __restrict__ new_idx, int* __restrict__ cnt) {
  int e = blockIdx.x * 256 + threadIdx.x;
  if (e >= N_EDGES) return;
  int s = new_idx[src[e]];
  int d = new_idx[dst[e]];
  if (s >= 0 && d >= 0) atomicAdd(&cnt[d], 1);
}

__global__ void csr_fill2_kernel(const int* __restrict__ src, const int* __restrict__ dst,
                                 const int* __restrict__ new_idx, int* __restrict__ cur,
                                 int* __restrict__ csr) {
  int e = blockIdx.x * 256 + threadIdx.x;
  if (e >= N_EDGES) return;
  int s = new_idx[src[e]];
  int d = new_idx[dst[e]];
  if (s < 0 || d < 0) return;
  int pos = atomicAdd(&cur[d], 1);
  csr[pos] = s;
}

// ------------- gather on INPUT features (conv1): G = A_norm . x -------------
// wave per dst node, lane = channel (64); 4-wide ILP on the edge loop

__global__ void agg_gather64_in_kernel(const void* __restrict__ xv, const int* __restrict__ rowstart,
                                       const int* __restrict__ csr, const float* __restrict__ dis,
                                       const Ctl* __restrict__ ctl, bf16* __restrict__ G, int M)
{
  const bool f32 = ctl->isfp32 != 0;
  int gid = blockIdx.x * 256 + threadIdx.x;
  int d = gid >> 6;
  int lane = gid & 63;
  if (d >= M) return;
  float dd = dis[d];
  float a = dd * dd * loadF(xv, (size_t)d * 64 + lane, f32);
  int i = rowstart[d], i1 = rowstart[d + 1];
  for (; i + 4 <= i1; i += 4) {
    int s0 = csr[i], s1 = csr[i + 1], s2 = csr[i + 2], s3 = csr[i + 3];
    float w0 = dd * dis[s0], w1 = dd * dis[s1], w2 = dd * dis[s2], w3 = dd * dis[s3];
    float v0 = loadF(xv, (size_t)s0 * 64 + lane, f32);
    float v1 = loadF(xv, (size_t)s1 * 64 + lane, f32);
    float v2 = loadF(xv, (size_t)s2 * 64 + lane, f32);
    float v3 = loadF(xv, (size_t)s3 * 64 + lane, f32);
    a += w0 * v0 + w1 * v1 + w2 * v2 + w3 * v3;
  }
  for (; i < i1; ++i) {
    int s = csr[i];
    a += dd * dis[s] * loadF(xv, (size_t)s * 64 + lane, f32);
  }
  G[(size_t)d * 64 + lane] = __float2bfloat16(a);
}

// ---------------- GEMMs (fp32 accumulate, bf16 out) ----------------

// conv1: Y[N,128] = G[N,64] @ W1 + b1, with fused pooling score/keys
__global__ void gemm_in_kernel(const bf16* __restrict__ G, const void* __restrict__ W,
                               const void* __restrict__ b, const void* __restrict__ pw,
                               bf16* __restrict__ Y, const Ctl* __restrict__ ctl,
                               float* __restrict__ score, u64* __restrict__ keys)
{
  __shared__ float Ws[64 * 128];
  __shared__ float Xs[32 * 64];
  const bool f32 = ctl->isfp32 != 0;
  const int tid = threadIdx.x;
  const int row0 = blockIdx.x * 32;

  for (int i = tid; i < 64 * 128; i += 256) Ws[i] = loadF(W, i, f32);
  const bf16x2* G2 = (const bf16x2*)G;
  for (int p = tid; p < 32 * 32; p += 256) {
    int r = p >> 5, kp = p & 31;
    int gr = row0 + r;
    float vx = 0.f, vy = 0.f;
    if (gr < N_NODES) {
      bf16x2 v = G2[(size_t)gr * 32 + kp];
      vx = bf2f(v.x); vy = bf2f(v.y);
    }
    Xs[r * 64 + 2 * kp]     = vx;
    Xs[r * 64 + 2 * kp + 1] = vy;
  }
  __syncthreads();

  const int tx = tid & 63;     // lane within wave
  const int ty = tid >> 6;     // wave id; wave handles rows ty*8..ty*8+7
  float acc[8][2];
  #pragma unroll
  for (int i = 0; i < 8; ++i) { acc[i][0] = 0.f; acc[i][1] = 0.f; }
  for (int k = 0; k < 64; ++k) {
    float w0 = Ws[k * 128 + tx];
    float w1 = Ws[k * 128 + tx + 64];
    #pragma unroll
    for (int i = 0; i < 8; ++i) {
      float xv = Xs[(ty * 8 + i) * 64 + k];
      acc[i][0] += xv * w0;
      acc[i][1] += xv * w1;
    }
  }
  float bv0 = loadF(b, tx, f32);
  float bv1 = loadF(b, tx + 64, f32);
  float pw0 = loadF(pw, tx, f32);
  float pw1 = loadF(pw, tx + 64, f32);
  float inv_norm = ctl->inv_norm;
  #pragma unroll
  for (int i = 0; i < 8; ++i) {
    int gr = row0 + ty * 8 + i;
    float h0 = acc[i][0] + bv0;
    float h1 = acc[i][1] + bv1;
    if (gr < N_NODES) {
      Y[(size_t)gr * 128 + tx]      = __float2bfloat16(h0);
      Y[(size_t)gr * 128 + tx + 64] = __float2bfloat16(h1);
    }
    float p = fmaxf(h0, 0.f) * pw0 + fmaxf(h1, 0.f) * pw1;
    for (int off = 32; off; off >>= 1) p += __shfl_down(p, off);
    if (tx == 0 && gr < N_NODES) {
      float sc = tanhf(p * inv_norm);
      score[gr] = sc;
      u32 u = __float_as_uint(sc);
      u = (u & 0x80000000u) ? ~u : (u | 0x80000000u);
      keys[gr] = (((u64)u) << 16) | (u64)(0xFFFFu - (u32)gr);  // 48-bit key
    }
  }
}

// Y[M,64] = (relu?)X[M,128] @ W[128,64]; X bf16; no bias (added downstream)
__global__ void gemm_128_64_kernel(const bf16* __restrict__ X, const void* __restrict__ W,
                                   bf16* __restrict__ Y, const Ctl* __restrict__ ctl,
                                   int M, int relu_x)
{
  __shared__ float Ws[128 * 64];
  __shared__ float Xs[32 * 128];
  const bool f32 = ctl->isfp32 != 0;
  const int tid = threadIdx.x;
  const int row0 = blockIdx.x * 32;

  for (int i = tid; i < 128 * 64; i += 256) Ws[i] = loadF(W, i, f32);
  const bf16x2* X2 = (const bf16x2*)X;
  for (int p = tid; p < 32 * 64; p += 256) {
    int r = p >> 6, kp = p & 63;
    int gr = row0 + r;
    float vx = 0.f, vy = 0.f;
    if (gr < M) {
      bf16x2 v = X2[(size_t)gr * 64 + kp];
      vx = bf2f(v.x); vy = bf2f(v.y);
      if (relu_x) { vx = fmaxf(vx, 0.f); vy = fmaxf(vy, 0.f); }
    }
    Xs[r * 128 + 2 * kp]     = vx;
    Xs[r * 128 + 2 * kp + 1] = vy;
  }
  __syncthreads();

  const int tx = tid & 31;
  const int ty = tid >> 5;
  float acc[4][2];
  #pragma unroll
  for (int i = 0; i < 4; ++i) { acc[i][0] = 0.f; acc[i][1] = 0.f; }
  for (int k = 0; k < 128; ++k) {
    float w0 = Ws[k * 64 + tx];
    float w1 = Ws[k * 64 + tx + 32];
    #pragma unroll
    for (int i = 0; i < 4; ++i) {
      float xv = Xs[(ty * 4 + i) * 128 + k];
      acc[i][0] += xv * w0;
      acc[i][1] += xv * w1;
    }
  }
  #pragma unroll
  for (int i = 0; i < 4; ++i) {
    int gr = row0 + ty * 4 + i;
    if (gr < M) {
      Y[(size_t)gr * 64 + tx]      = __float2bfloat16(acc[i][0]);
      Y[(size_t)gr * 64 + tx + 32] = __float2bfloat16(acc[i][1]);
    }
  }
}

// conv3: Y[M,128] = X[M,64] @ W[64,128] + b; X bf16 (already aggregated)
__global__ void gemm_64_128_kernel(const bf16* __restrict__ X, const void* __restrict__ W,
                                   const void* __restrict__ b, bf16* __restrict__ Y,
                                   const Ctl* __restrict__ ctl, int M)
{
  __shared__ float Ws[64 * 128];
  __shared__ float Xs[32 * 64];
  const bool f32 = ctl->isfp32 != 0;
  const int tid = threadIdx.x;
  const int row0 = blockIdx.x * 32;

  for (int i = tid; i < 64 * 128; i += 256) Ws[i] = loadF(W, i, f32);
  const bf16x2* X2 = (const bf16x2*)X;
  for (int p = tid; p < 32 * 32; p += 256) {
    int r = p >> 5, kp = p & 31;
    int gr = row0 + r;
    float vx = 0.f, vy = 0.f;
    if (gr < M) {
      bf16x2 v = X2[(size_t)gr * 32 + kp];
      vx = bf2f(v.x); vy = bf2f(v.y);
    }
    Xs[r * 64 + 2 * kp]     = vx;
    Xs[r * 64 + 2 * kp + 1] = vy;
  }
  __syncthreads();

  const int tx = tid & 63;
  const int ty = tid >> 6;
  float acc[8][2];
  #pragma unroll
  for (int i = 0; i < 8; ++i) { acc[i][0] = 0.f; acc[i][1] = 0.f; }
  for (int k = 0; k < 64; ++k) {
    float w0 = Ws[k * 128 + tx];
    float w1 = Ws[k * 128 + tx + 64];
    #pragma unroll
    for (int i = 0; i < 8; ++i) {
      float xv = Xs[(ty * 8 + i) * 64 + k];
      acc[i][0] += xv * w0;
      acc[i][1] += xv * w1;
    }
  }
  float bv0 = loadF(b, tx, f32);
  float bv1 = loadF(b, tx + 64, f32);
  #pragma unroll
  for (int i = 0; i < 8; ++i) {
    int gr = row0 + ty * 8 + i;
    if (gr < M) {
      Y[(size_t)gr * 128 + tx]      = __float2bfloat16(acc[i][0] + bv0);
      Y[(size_t)gr * 128 + tx + 64] = __float2bfloat16(acc[i][1] + bv1);
    }
  }
}

// --------- gather on bf16 rows (64 ch), optional relu/bias; ILP-4 ---------

__global__ void agg_gather64_kernel(const bf16* __restrict__ hW, const int* __restrict__ rowstart,
                                    const int* __restrict__ csr, const float* __restrict__ dis,
                                    const void* __restrict__ b, const Ctl* __restrict__ ctl,
                                    bf16* __restrict__ agg, int M, int relusrc, int addbias)
{
  const bool f32 = ctl->isfp32 != 0;
  int gid = blockIdx.x * 256 + threadIdx.x;
  int d = gid >> 6;
  int lane = gid & 63;
  if (d >= M) return;
  float dd = dis[d];
  float v = bf2f(hW[(size_t)d * 64 + lane]);
  if (relusrc) v = fmaxf(v, 0.f);
  float a = v * dd * dd + (addbias ? loadF(b, lane, f32) : 0.f);
  int i = rowstart[d], i1 = rowstart[d + 1];
  for (; i + 4 <= i1; i += 4) {
    int s0 = csr[i], s1 = csr[i + 1], s2 = csr[i + 2], s3 = csr[i + 3];
    float w0 = dd * dis[s0], w1 = dd * dis[s1], w2 = dd * dis[s2], w3 = dd * dis[s3];
    float v0 = bf2f(hW[(size_t)s0 * 64 + lane]);
    float v1 = bf2f(hW[(size_t)s1 * 64 + lane]);
    float v2 = bf2f(hW[(size_t)s2 * 64 + lane]);
    float v3 = bf2f(hW[(size_t)s3 * 64 + lane]);
    if (relusrc) {
      v0 = fmaxf(v0, 0.f); v1 = fmaxf(v1, 0.f); v2 = fmaxf(v2, 0.f); v3 = fmaxf(v3, 0.f);
    }
    a += w0 * v0 + w1 * v1 + w2 * v2 + w3 * v3;
  }
  for (; i < i1; ++i) {
    int s = csr[i];
    float vv = bf2f(hW[(size_t)s * 64 + lane]);
    if (relusrc) vv = fmaxf(vv, 0.f);
    a += dd * dis[s] * vv;
  }
  agg[(size_t)d * 64 + lane] = __float2bfloat16(a);
}

// conv4: gather + bias + per-block mean-pool partial (plain stores, no atomics)
__global__ void agg_gather64_final_kernel(const bf16* __restrict__ hW, const int* __restrict__ rowstart,
                                          const int* __restrict__ csr, const float* __restrict__ dis,
                                          const void* __restrict__ b, const Ctl* __restrict__ ctl,
                                          float* __restrict__ partial, int M)
{
  __shared__ float cs[64];
  const bool f32 = ctl->isfp32 != 0;
  int tid = threadIdx.x;
  if (tid < 64) cs[tid] = 0.f;
  __syncthreads();
  int gid = blockIdx.x * 256 + tid;
  int d = gid >> 6;
  int lane = gid & 63;
  if (d < M) {
    float dd = dis[d];
    float a = bf2f(hW[(size_t)d * 64 + lane]) * (dd * dd) + loadF(b, lane, f32);
    int i = rowstart[d], i1 = rowstart[d + 1];
    for (; i + 4 <= i1; i += 4) {
      int s0 = csr[i], s1 = csr[i + 1], s2 = csr[i + 2], s3 = csr[i + 3];
      float w0 = dd * dis[s0], w1 = dd * dis[s1], w2 = dd * dis[s2], w3 = dd * dis[s3];
      float v0 = bf2f(hW[(size_t)s0 * 64 + lane]);
      float v1 = bf2f(hW[(size_t)s1 * 64 + lane]);
      float v2 = bf2f(hW[(size_t)s2 * 64 + lane]);
      float v3 = bf2f(hW[(size_t)s3 * 64 + lane]);
      a += w0 * v0 + w1 * v1 + w2 * v2 + w3 * v3;
    }
    for (; i < i1; ++i) {
      int s = csr[i];
      a += dd * dis[s] * bf2f(hW[(size_t)s * 64 + lane]);
    }
    atomicAdd(&cs[lane], a);  // LDS, 4-way only
  }
  __syncthreads();
  if (tid < 64) partial[(size_t)tid * gridDim.x + blockIdx.x] = cs[tid];
}

// 64 blocks: block c sums partial[c][*] and writes out[c]
__global__ void reduce_out_kernel(const float* __restrict__ partial, const Ctl* __restrict__ ctl,
                                  void* __restrict__ out, int nblk)
{
  __shared__ float sh[256];
  int c = blockIdx.x;
  float s = 0.f;
  for (int j = threadIdx.x; j < nblk; j += 256) s += partial[(size_t)c * nblk + j];
  sh[threadIdx.x] = s;
  __syncthreads();
  for (int st = 128; st > 0; st >>= 1) {
    if (threadIdx.x < st) sh[threadIdx.x] += sh[threadIdx.x + st];
    __syncthreads();
  }
  if (threadIdx.x == 0) {
    float val = sh[0] / (float)K_KEEP;
    if (ctl->isfp32) ((float*)out)[c] = val;
    else             ((bf16*)out)[c] = __float2bfloat16(val);
  }
}

// ---------------- TopK select (R5-proven fused hist+pick) ----------------

__global__ void histpick_kernel(const u64* __restrict__ keys, Ctl* ctl, int shift, int nblocks) {
  __shared__ u32 lh[256];
  __shared__ int lastflag;
  const int tid = threadIdx.x;
  lh[tid] = 0;
  __syncthreads();
  u64 prefix = ctl->prefix;
  int i = blockIdx.x * 256 + tid;
  if (i < N_NODES) {
    u64 key = keys[i];
    if ((key >> (shift + 8)) == (prefix >> (shift + 8)))
      atomicAdd(&lh[(u32)((key >> shift) & 0xFF)], 1u);
  }
  __syncthreads();
  u32 c = lh[tid];
  if (c) atomicAdd(&ctl->hist[tid], c);
  __syncthreads();
  if (tid == 0) {
    __threadfence();
    u32 old = atomicAdd(&ctl->done, 1u);
    lastflag = (old == (u32)(nblocks - 1));
  }
  __syncthreads();
  if (!lastflag) return;
  lh[tid] = atomicExch(&ctl->hist[tid], 0u);
  __syncthreads();
  if (tid == 0) {
    u32 kr = ctl->kremain;
    u32 cum = 0;
    int sel = 0;
    for (int v = 255; v >= 0; --v) {
      u32 cc = lh[v];
      if (cum + cc >= kr) { sel = v; break; }
      cum += cc;
    }
    ctl->prefix = prefix | (((u64)sel) << shift);
    ctl->kremain = kr - cum;
    ctl->done = 0u;
  }
}

__global__ void mark_kernel(const u64* __restrict__ keys, Ctl* ctl,
                            int* __restrict__ new_idx, int* __restrict__ kept)
{
  int i = blockIdx.x * 256 + threadIdx.x;
  if (i >= N_NODES) return;
  if (keys[i] >= ctl->prefix) {
    int pos = (int)atomicAdd(&ctl->cnt, 1u);
    new_idx[i] = pos;
    kept[pos] = i;
  } else {
    new_idx[i] = -1;
  }
}

// hp[pos] = relu(h[orig]) * score[orig]; wave per row, bf16x2
__global__ void hp_kernel(const bf16* __restrict__ h, const int* __restrict__ kept,
                          const float* __restrict__ score, bf16* __restrict__ hp)
{
  int gid = blockIdx.x * 256 + threadIdx.x;
  int row = gid >> 6;
  int lane = gid & 63;
  if (row >= K_KEEP) return;
  int o = kept[row];
  float s = score[o];
  bf16x2 v = ((const bf16x2*)h)[(size_t)o * 64 + lane];
  bf16x2 w;
  w.x = __float2bfloat16(fmaxf(bf2f(v.x), 0.f) * s);
  w.y = __float2bfloat16(fmaxf(bf2f(v.y), 0.f) * s);
  ((bf16x2*)hp)[(size_t)row * 64 + lane] = w;
}

// ---------------- launch ----------------

extern "C" void kernel_launch(void* const* d_in, const int* in_sizes, int n_in,
                              void* d_out, int out_size, void* d_ws, size_t ws_size,
                              hipStream_t stream)
{
  const void* x  = d_in[0];
  const int*  ei = (const int*)d_in[1];
  const void* W1 = d_in[3];
  const void* b1 = d_in[4];
  const void* pw = d_in[5];
  const void* W2 = d_in[6];
  const void* b2 = d_in[7];
  const void* W3 = d_in[8];
  const void* b3 = d_in[9];
  const void* W4 = d_in[10];
  const void* b4 = d_in[11];

  const int* src = ei;
  const int* dst = ei + N_EDGES;

  float* F = (float*)d_ws;
  bf16*  A16       = (bf16*)F;               // N x 128 bf16
  bf16*  B16       = (bf16*)(F + 3200000);   // N x 128 bf16
  bf16*  C16       = (bf16*)(F + 6400000);   // K x 128 bf16 (also conv1's G [N x 64])
  float* dis1      = F + 9000000;
  float* dis2      = F + 9050000;
  float* score     = F + 9100000;
  u64*   keys      = (u64*)(F + 9150000);
  int*   new_idx   = (int*)(F + 9250000);
  int*   kept      = (int*)(F + 9300000);
  int*   cnt1      = (int*)(F + 9350000);
  int*   rowstart1 = (int*)(F + 9400000);
  int*   cnt2      = (int*)(F + 9450004);
  int*   rowstart2 = (int*)(F + 9490004);
  int*   csr1      = (int*)(F + 9530008);
  int*   csr2      = (int*)(F + 10330008);
  Ctl*   ctl       = (Ctl*)(F + 11130008);
  int*   bsum      = (int*)(F + 11131000);
  int*   boff      = (int*)(F + 11131256);
  int*   detcnt    = (int*)(F + 11131512);
  float* partial   = F + 11131576;           // 64 x 10000 fp32 = 2.56 MB (total ~47.1 MB)

  const int EB  = (N_EDGES + 255) / 256;     // 3125
  const int NB1 = (N_NODES + 255) / 256;     // 196
  const int NB2 = (K_KEEP + 255) / 256;      // 157
  const int GFB = K_KEEP / 4;                // 10000 final-gather blocks

  init_kernel<<<NB1, 256, 0, stream>>>((const unsigned short*)x, cnt1, cnt2, detcnt, ctl);
  norm_kernel<<<1, 64, 0, stream>>>(pw, detcnt, ctl);

  // CSR graph 1
  csr_count1_kernel<<<EB, 256, 0, stream>>>(dst, cnt1);
  block_reduce_kernel<<<NB1, 256, 0, stream>>>(cnt1, bsum, N_NODES);
  scan_bsum_kernel<<<1, 256, 0, stream>>>(bsum, boff, NB1, &rowstart1[N_NODES]);
  block_scanout_kernel<<<NB1, 256, 0, stream>>>(cnt1, boff, rowstart1, dis1, N_NODES);
  csr_fill1_kernel<<<EB, 256, 0, stream>>>(src, dst, cnt1, csr1);

  // conv1 (gather-first): G = A_norm . x ; h1 = G @ W1 + b1 (+fused score)
  agg_gather64_in_kernel<<<(N_NODES + 3) / 4, 256, 0, stream>>>(x, rowstart1, csr1, dis1, ctl, C16, N_NODES);
  gemm_in_kernel<<<(N_NODES + 31) / 32, 256, 0, stream>>>(C16, W1, b1, pw, B16, ctl, score, keys);

  // top-K select (6 x 8-bit radix over 48-bit keys)
  for (int p = 0; p < 6; ++p)
    histpick_kernel<<<NB1, 256, 0, stream>>>(keys, ctl, 40 - 8 * p, NB1);
  mark_kernel<<<NB1, 256, 0, stream>>>(keys, ctl, new_idx, kept);
  hp_kernel<<<(K_KEEP + 3) / 4, 256, 0, stream>>>(B16, kept, score, C16);

  // CSR pooled graph
  csr_count2_kernel<<<EB, 256, 0, stream>>>(src, dst, new_idx, cnt2);
  block_reduce_kernel<<<NB2, 256, 0, stream>>>(cnt2, bsum, K_KEEP);
  scan_bsum_kernel<<<1, 256, 0, stream>>>(bsum, boff, NB2, &rowstart2[K_KEEP]);
  block_scanout_kernel<<<NB2, 256, 0, stream>>>(cnt2, boff, rowstart2, dis2, K_KEEP);
  csr_fill2_kernel<<<EB, 256, 0, stream>>>(src, dst, new_idx, cnt2, csr2);

  // conv2: gemm-first (out 64 < in 128): A = hp @ W2 ; h2 = gather(A) + b2
  gemm_128_64_kernel<<<K_KEEP / 32, 256, 0, stream>>>(C16, W2, A16, ctl, K_KEEP, 0);
  agg_gather64_kernel<<<K_KEEP / 4, 256, 0, stream>>>(A16, rowstart2, csr2, dis2, b2, ctl, B16, K_KEEP, 0, 1);

  // conv3: gather-first (out 128 > in 64): G = gather(relu(h2)) ; h3 = G @ W3 + b3
  agg_gather64_kernel<<<K_KEEP / 4, 256, 0, stream>>>(B16, rowstart2, csr2, dis2, b3, ctl, A16, K_KEEP, 1, 0);
  gemm_64_128_kernel<<<K_KEEP / 32, 256, 0, stream>>>(A16, W3, b3, B16, ctl, K_KEEP);

  // conv4: gemm-first: A = relu(h3) @ W4 ; out partials = gather(A) + b4
  gemm_128_64_kernel<<<K_KEEP / 32, 256, 0, stream>>>(B16, W4, A16, ctl, K_KEEP, 1);
  agg_gather64_final_kernel<<<GFB, 256, 0, stream>>>(A16, rowstart2, csr2, dis2, b4, ctl, partial, K_KEEP);

  reduce_out_kernel<<<64, 256, 0, stream>>>(partial, ctl, d_out, GFB);
}

// Round 8
// 487.380 us; speedup vs baseline: 2.6329x; 1.1907x over previous
//
#include <hip/hip_runtime.h>
#include <hip/hip_bf16.h>
#include <stdint.h>

#define N_NODES 50000
#define N_EDGES 800000
#define K_KEEP  40000
#define BKT     196        // ceil(N_NODES/256) dst-range buckets
#define BCAP    6144       // per-bucket capacity (mean 4081, +32 sigma)

typedef unsigned long long u64;
typedef unsigned int u32;
typedef __hip_bfloat16 bf16;
typedef __hip_bfloat162 bf16x2;

struct Ctl {
  u64 prefix;
  u32 kremain;
  u32 cnt;
  float inv_norm;
  u32 isfp32;
  u32 done;
  u32 pad;
  u32 hist[256];
};

__device__ __forceinline__ float bf2f(bf16 v) { return __bfloat162float(v); }
__device__ __forceinline__ float loadF(const void* p, size_t i, bool f32) {
  return f32 ? ((const float*)p)[i] : bf2f(((const bf16*)p)[i]);
}

// ---------------- init (+parallel dtype detect, proven R5-R7) ----------------

__global__ void init_kernel(const unsigned short* __restrict__ x16,
                            int* __restrict__ bucket_cur, int* __restrict__ detcnt, Ctl* ctl) {
  __shared__ u32 dsh[256];
  int i = blockIdx.x * 256 + threadIdx.x;
  if (i < BKT) bucket_cur[i] = i * BCAP;
  if (blockIdx.x == 0) {
    ctl->hist[threadIdx.x] = 0u;
    if (threadIdx.x == 0) { ctl->prefix = 0ull; ctl->kremain = K_KEEP; ctl->cnt = 0u; ctl->done = 0u; }
  }
  if (blockIdx.x < 64) {
    int base = blockIdx.x * 2048;
    u32 c = 0;
    for (int j = threadIdx.x; j < 2048; j += 256) {
      u32 h = x16[base + j];
      if ((h & 0x7F80u) == 0x7F80u) c++;
    }
    dsh[threadIdx.x] = c;
    __syncthreads();
    for (int s = 128; s > 0; s >>= 1) {
      if (threadIdx.x < s) dsh[threadIdx.x] += dsh[threadIdx.x + s];
      __syncthreads();
    }
    if (threadIdx.x == 0) detcnt[blockIdx.x] = (int)dsh[0];
  }
}

__global__ void norm_kernel(const void* __restrict__ pw, const int* __restrict__ detcnt, Ctl* ctl) {
  int lane = threadIdx.x;   // 64
  int dc = detcnt[lane];
  for (int off = 32; off; off >>= 1) dc += __shfl_down(dc, off);
  dc = __shfl(dc, 0);
  bool f32 = (dc >= 16);
  float v0 = loadF(pw, lane, f32);
  float v1 = loadF(pw, 64 + lane, f32);
  float s = v0 * v0 + v1 * v1;
  for (int off = 32; off; off >>= 1) s += __shfl_down(s, off);
  if (lane == 0) {
    ctl->inv_norm = 1.0f / sqrtf(s);
    ctl->isfp32 = f32 ? 1u : 0u;
  }
}

// ------------- CSR1 via bucket sort (R7: random 4B scatter cost 52MB WRITE) -------------

// 2048 edges/block: LDS-aggregated bucket reservation, then scatter packed
// (src<<8 | dst&255) into per-bucket streams (sequential within bucket).
__global__ void bucket_scatter_kernel(const int* __restrict__ src, const int* __restrict__ dst,
                                      int* __restrict__ bucket_cur, u32* __restrict__ bucketbuf)
{
  __shared__ u32 hist[BKT];
  __shared__ u32 base[BKT];
  const int tid = threadIdx.x;
  const int e0 = blockIdx.x * 2048;
  for (int t = tid; t < BKT; t += 256) hist[t] = 0;
  __syncthreads();
  #pragma unroll
  for (int j = 0; j < 8; ++j) {
    int e = e0 + j * 256 + tid;
    if (e < N_EDGES) atomicAdd(&hist[dst[e] >> 8], 1u);
  }
  __syncthreads();
  for (int t = tid; t < BKT; t += 256) {
    u32 c = hist[t];
    base[t] = c ? (u32)atomicAdd(&bucket_cur[t], (int)c) : 0u;
    hist[t] = 0;   // becomes local cursor
  }
  __syncthreads();
  #pragma unroll
  for (int j = 0; j < 8; ++j) {
    int e = e0 + j * 256 + tid;
    if (e < N_EDGES) {
      int d = dst[e];
      int b = d >> 8;
      u32 pos = base[b] + atomicAdd(&hist[b], 1u);
      bucketbuf[pos] = ((u32)src[e] << 8) | (u32)(d & 255);
    }
  }
}

// scan bucket sizes -> boff (exclusive); rowstart1[N] = total
__global__ void scan_buckets_kernel(const int* __restrict__ bucket_cur, int* __restrict__ boff,
                                    int* __restrict__ rowstart_n)
{
  __shared__ int sh[256];
  int tid = threadIdx.x;
  int v = (tid < BKT) ? (bucket_cur[tid] - tid * BCAP) : 0;
  sh[tid] = v;
  __syncthreads();
  for (int off = 1; off < 256; off <<= 1) {
    int t = (tid >= off) ? sh[tid - off] : 0;
    __syncthreads();
    sh[tid] += t;
    __syncthreads();
  }
  if (tid < BKT) boff[tid] = sh[tid] - v;
  if (tid == 255) *rowstart_n = sh[255];
}

// block per bucket: count 256-node window in LDS, scan, emit rowstart/dis/csr
// (csr writes land in a ~16KB contiguous window -> full cachelines)
__global__ void csr_from_buckets_kernel(const u32* __restrict__ bucketbuf, const int* __restrict__ bucket_cur,
                                        const int* __restrict__ boff, int* __restrict__ rowstart,
                                        float* __restrict__ dis, int* __restrict__ csr)
{
  __shared__ u32 cnt[256];
  __shared__ u32 loc[256];
  __shared__ u32 cur[256];
  const int b = blockIdx.x;
  const int tid = threadIdx.x;
  const int bc = bucket_cur[b] - b * BCAP;
  const u32* buf = bucketbuf + (size_t)b * BCAP;
  const int off0 = boff[b];
  cnt[tid] = 0;
  __syncthreads();
  for (int i = tid; i < bc; i += 256) atomicAdd(&cnt[buf[i] & 255u], 1u);
  __syncthreads();
  u32 c = cnt[tid];
  loc[tid] = c;
  __syncthreads();
  for (int off = 1; off < 256; off <<= 1) {
    u32 t = (tid >= off) ? loc[tid - off] : 0;
    __syncthreads();
    loc[tid] += t;
    __syncthreads();
  }
  int node = b * 256 + tid;
  u32 excl = loc[tid] - c;
  if (node < N_NODES) {
    rowstart[node] = off0 + (int)excl;
    dis[node] = rsqrtf(1.0f + (float)c);
  }
  cur[tid] = off0 + excl;
  __syncthreads();
  for (int i = tid; i < bc; i += 256) {
    u32 p = buf[i];
    u32 pos = atomicAdd(&cur[p & 255u], 1u);
    csr[pos] = (int)(p >> 8);
  }
}

// ---------------- hierarchical scan (graph2 only) ----------------

__global__ void block_reduce_kernel(const int* __restrict__ cnt, int* __restrict__ bsum, int n) {
  __shared__ int sh[256];
  int i = blockIdx.x * 256 + threadIdx.x;
  sh[threadIdx.x] = (i < n) ? cnt[i] : 0;
  __syncthreads();
  for (int s = 128; s > 0; s >>= 1) {
    if (threadIdx.x < s) sh[threadIdx.x] += sh[threadIdx.x + s];
    __syncthreads();
  }
  if (threadIdx.x == 0) bsum[blockIdx.x] = sh[0];
}

__global__ void scan_bsum_kernel(const int* __restrict__ bsum, int* __restrict__ boff,
                                 int nb, int* __restrict__ rowstart_n) {
  __shared__ int sh[256];
  int tid = threadIdx.x;
  int v = (tid < nb) ? bsum[tid] : 0;
  sh[tid] = v;
  __syncthreads();
  for (int off = 1; off < 256; off <<= 1) {
    int t = (tid >= off) ? sh[tid - off] : 0;
    __syncthreads();
    sh[tid] += t;
    __syncthreads();
  }
  if (tid < nb) boff[tid] = sh[tid] - v;
  if (tid == 255) *rowstart_n = sh[255];
}

__global__ void block_scanout_kernel(const int* __restrict__ cnt, const int* __restrict__ boff,
                                     int* __restrict__ rowstart, float* __restrict__ dis, int n) {
  __shared__ int sh[256];
  int tid = threadIdx.x;
  int i = blockIdx.x * 256 + tid;
  int c = (i < n) ? cnt[i] : 0;
  sh[tid] = c;
  __syncthreads();
  for (int off = 1; off < 256; off <<= 1) {
    int t = (tid >= off) ? sh[tid - off] : 0;
    __syncthreads();
    sh[tid] += t;
    __syncthreads();
  }
  if (i < n) {
    rowstart[i] = boff[blockIdx.x] + sh[tid] - c;
    dis[i] = rsqrtf(1.0f + (float)c);
  }
}

// ------- CSR2 from CSR1: filter-compact kept rows (no atomic scatter) -------

// 16-lane subgroup per pooled node: count valid neighbors
__global__ void cnt2_kernel(const int* __restrict__ kept, const int* __restrict__ rowstart1,
                            const int* __restrict__ csr1, const int* __restrict__ new_idx,
                            int* __restrict__ cnt2)
{
  int gid = blockIdx.x * 256 + threadIdx.x;
  int kp = gid >> 4;
  int l16 = gid & 15;
  if (kp >= K_KEEP) return;
  int o = kept[kp];
  int i0 = rowstart1[o], i1 = rowstart1[o + 1];
  int c = 0;
  for (int i = i0 + l16; i < i1; i += 16) c += (new_idx[csr1[i]] >= 0);
  c += __shfl_down(c, 8, 16);
  c += __shfl_down(c, 4, 16);
  c += __shfl_down(c, 2, 16);
  c += __shfl_down(c, 1, 16);
  if (l16 == 0) cnt2[kp] = c;
}

// 16-lane subgroup per pooled node: ballot-rank compaction into csr2
__global__ void fill2_kernel(const int* __restrict__ kept, const int* __restrict__ rowstart1,
                             const int* __restrict__ csr1, const int* __restrict__ new_idx,
                             const int* __restrict__ rowstart2, int* __restrict__ csr2)
{
  int gid = blockIdx.x * 256 + threadIdx.x;
  int kp = gid >> 4;
  int l16 = gid & 15;
  if (kp >= K_KEEP) return;
  int o = kept[kp];
  int i0 = rowstart1[o], i1 = rowstart1[o + 1];
  int base = rowstart2[kp];
  int sub = (threadIdx.x & 63) >> 4;
  for (int ib = i0; ib < i1; ib += 16) {
    int i = ib + l16;
    int ns = -1;
    if (i < i1) ns = new_idx[csr1[i]];
    u64 bal = __ballot(ns >= 0);
    u32 m = (u32)((bal >> (sub * 16)) & 0xFFFFull);
    if (ns >= 0) {
      int rank = __popc(m & ((1u << l16) - 1u));
      csr2[base + rank] = ns;
    }
    base += __popc(m);
  }
}

// ------------- conv1 gather on input features; ILP-4 (proven R7) -------------

__global__ void agg_gather64_in_kernel(const void* __restrict__ xv, const int* __restrict__ rowstart,
                                       const int* __restrict__ csr, const float* __restrict__ dis,
                                       const Ctl* __restrict__ ctl, bf16* __restrict__ G, int M)
{
  const bool f32 = ctl->isfp32 != 0;
  int gid = blockIdx.x * 256 + threadIdx.x;
  int d = gid >> 6;
  int lane = gid & 63;
  if (d >= M) return;
  float dd = dis[d];
  float a = dd * dd * loadF(xv, (size_t)d * 64 + lane, f32);
  int i = rowstart[d], i1 = rowstart[d + 1];
  for (; i + 4 <= i1; i += 4) {
    int s0 = csr[i], s1 = csr[i + 1], s2 = csr[i + 2], s3 = csr[i + 3];
    float w0 = dd * dis[s0], w1 = dd * dis[s1], w2 = dd * dis[s2], w3 = dd * dis[s3];
    float v0 = loadF(xv, (size_t)s0 * 64 + lane, f32);
    float v1 = loadF(xv, (size_t)s1 * 64 + lane, f32);
    float v2 = loadF(xv, (size_t)s2 * 64 + lane, f32);
    float v3 = loadF(xv, (size_t)s3 * 64 + lane, f32);
    a += w0 * v0 + w1 * v1 + w2 * v2 + w3 * v3;
  }
  for (; i < i1; ++i) {
    int s = csr[i];
    a += dd * dis[s] * loadF(xv, (size_t)s * 64 + lane, f32);
  }
  G[(size_t)d * 64 + lane] = __float2bfloat16(a);
}

// ---------------- GEMMs (fp32 accumulate, bf16 out) ----------------

__global__ void gemm_in_kernel(const bf16* __restrict__ G, const void* __restrict__ W,
                               const void* __restrict__ b, const void* __restrict__ pw,
                               bf16* __restrict__ Y, const Ctl* __restrict__ ctl,
                               float* __restrict__ score, u64* __restrict__ keys)
{
  __shared__ float Ws[64 * 128];
  __shared__ float Xs[32 * 64];
  const bool f32 = ctl->isfp32 != 0;
  const int tid = threadIdx.x;
  const int row0 = blockIdx.x * 32;

  for (int i = tid; i < 64 * 128; i += 256) Ws[i] = loadF(W, i, f32);
  const bf16x2* G2 = (const bf16x2*)G;
  for (int p = tid; p < 32 * 32; p += 256) {
    int r = p >> 5, kp = p & 31;
    int gr = row0 + r;
    float vx = 0.f, vy = 0.f;
    if (gr < N_NODES) {
      bf16x2 v = G2[(size_t)gr * 32 + kp];
      vx = bf2f(v.x); vy = bf2f(v.y);
    }
    Xs[r * 64 + 2 * kp]     = vx;
    Xs[r * 64 + 2 * kp + 1] = vy;
  }
  __syncthreads();

  const int tx = tid & 63;
  const int ty = tid >> 6;
  float acc[8][2];
  #pragma unroll
  for (int i = 0; i < 8; ++i) { acc[i][0] = 0.f; acc[i][1] = 0.f; }
  for (int k = 0; k < 64; ++k) {
    float w0 = Ws[k * 128 + tx];
    float w1 = Ws[k * 128 + tx + 64];
    #pragma unroll
    for (int i = 0; i < 8; ++i) {
      float xv = Xs[(ty * 8 + i) * 64 + k];
      acc[i][0] += xv * w0;
      acc[i][1] += xv * w1;
    }
  }
  float bv0 = loadF(b, tx, f32);
  float bv1 = loadF(b, tx + 64, f32);
  float pw0 = loadF(pw, tx, f32);
  float pw1 = loadF(pw, tx + 64, f32);
  float inv_norm = ctl->inv_norm;
  #pragma unroll
  for (int i = 0; i < 8; ++i) {
    int gr = row0 + ty * 8 + i;
    float h0 = acc[i][0] + bv0;
    float h1 = acc[i][1] + bv1;
    if (gr < N_NODES) {
      Y[(size_t)gr * 128 + tx]      = __float2bfloat16(h0);
      Y[(size_t)gr * 128 + tx + 64] = __float2bfloat16(h1);
    }
    float p = fmaxf(h0, 0.f) * pw0 + fmaxf(h1, 0.f) * pw1;
    for (int off = 32; off; off >>= 1) p += __shfl_down(p, off);
    if (tx == 0 && gr < N_NODES) {
      float sc = tanhf(p * inv_norm);
      score[gr] = sc;
      u32 u = __float_as_uint(sc);
      u = (u & 0x80000000u) ? ~u : (u | 0x80000000u);
      keys[gr] = (((u64)u) << 16) | (u64)(0xFFFFu - (u32)gr);
    }
  }
}

__global__ void gemm_128_64_kernel(const bf16* __restrict__ X, const void* __restrict__ W,
                                   bf16* __restrict__ Y, const Ctl* __restrict__ ctl,
                                   int M, int relu_x)
{
  __shared__ float Ws[128 * 64];
  __shared__ float Xs[32 * 128];
  const bool f32 = ctl->isfp32 != 0;
  const int tid = threadIdx.x;
  const int row0 = blockIdx.x * 32;

  for (int i = tid; i < 128 * 64; i += 256) Ws[i] = loadF(W, i, f32);
  const bf16x2* X2 = (const bf16x2*)X;
  for (int p = tid; p < 32 * 64; p += 256) {
    int r = p >> 6, kp = p & 63;
    int gr = row0 + r;
    float vx = 0.f, vy = 0.f;
    if (gr < M) {
      bf16x2 v = X2[(size_t)gr * 64 + kp];
      vx = bf2f(v.x); vy = bf2f(v.y);
      if (relu_x) { vx = fmaxf(vx, 0.f); vy = fmaxf(vy, 0.f); }
    }
    Xs[r * 128 + 2 * kp]     = vx;
    Xs[r * 128 + 2 * kp + 1] = vy;
  }
  __syncthreads();

  const int tx = tid & 31;
  const int ty = tid >> 5;
  float acc[4][2];
  #pragma unroll
  for (int i = 0; i < 4; ++i) { acc[i][0] = 0.f; acc[i][1] = 0.f; }
  for (int k = 0; k < 128; ++k) {
    float w0 = Ws[k * 64 + tx];
    float w1 = Ws[k * 64 + tx + 32];
    #pragma unroll
    for (int i = 0; i < 4; ++i) {
      float xv = Xs[(ty * 4 + i) * 128 + k];
      acc[i][0] += xv * w0;
      acc[i][1] += xv * w1;
    }
  }
  #pragma unroll
  for (int i = 0; i < 4; ++i) {
    int gr = row0 + ty * 4 + i;
    if (gr < M) {
      Y[(size_t)gr * 64 + tx]      = __float2bfloat16(acc[i][0]);
      Y[(size_t)gr * 64 + tx + 32] = __float2bfloat16(acc[i][1]);
    }
  }
}

__global__ void gemm_64_128_kernel(const bf16* __restrict__ X, const void* __restrict__ W,
                                   const void* __restrict__ b, bf16* __restrict__ Y,
                                   const Ctl* __restrict__ ctl, int M)
{
  __shared__ float Ws[64 * 128];
  __shared__ float Xs[32 * 64];
  const bool f32 = ctl->isfp32 != 0;
  const int tid = threadIdx.x;
  const int row0 = blockIdx.x * 32;

  for (int i = tid; i < 64 * 128; i += 256) Ws[i] = loadF(W, i, f32);
  const bf16x2* X2 = (const bf16x2*)X;
  for (int p = tid; p < 32 * 32; p += 256) {
    int r = p >> 5, kp = p & 31;
    int gr = row0 + r;
    float vx = 0.f, vy = 0.f;
    if (gr < M) {
      bf16x2 v = X2[(size_t)gr * 32 + kp];
      vx = bf2f(v.x); vy = bf2f(v.y);
    }
    Xs[r * 64 + 2 * kp]     = vx;
    Xs[r * 64 + 2 * kp + 1] = vy;
  }
  __syncthreads();

  const int tx = tid & 63;
  const int ty = tid >> 6;
  float acc[8][2];
  #pragma unroll
  for (int i = 0; i < 8; ++i) { acc[i][0] = 0.f; acc[i][1] = 0.f; }
  for (int k = 0; k < 64; ++k) {
    float w0 = Ws[k * 128 + tx];
    float w1 = Ws[k * 128 + tx + 64];
    #pragma unroll
    for (int i = 0; i < 8; ++i) {
      float xv = Xs[(ty * 8 + i) * 64 + k];
      acc[i][0] += xv * w0;
      acc[i][1] += xv * w1;
    }
  }
  float bv0 = loadF(b, tx, f32);
  float bv1 = loadF(b, tx + 64, f32);
  #pragma unroll
  for (int i = 0; i < 8; ++i) {
    int gr = row0 + ty * 8 + i;
    if (gr < M) {
      Y[(size_t)gr * 128 + tx]      = __float2bfloat16(acc[i][0] + bv0);
      Y[(size_t)gr * 128 + tx + 64] = __float2bfloat16(acc[i][1] + bv1);
    }
  }
}

// --------- gather on bf16 rows (64 ch), optional relu/bias; ILP-4 ---------

__global__ void agg_gather64_kernel(const bf16* __restrict__ hW, const int* __restrict__ rowstart,
                                    const int* __restrict__ csr, const float* __restrict__ dis,
                                    const void* __restrict__ b, const Ctl* __restrict__ ctl,
                                    bf16* __restrict__ agg, int M, int relusrc, int addbias)
{
  const bool f32 = ctl->isfp32 != 0;
  int gid = blockIdx.x * 256 + threadIdx.x;
  int d = gid >> 6;
  int lane = gid & 63;
  if (d >= M) return;
  float dd = dis[d];
  float v = bf2f(hW[(size_t)d * 64 + lane]);
  if (relusrc) v = fmaxf(v, 0.f);
  float a = v * dd * dd + (addbias ? loadF(b, lane, f32) : 0.f);
  int i = rowstart[d], i1 = rowstart[d + 1];
  for (; i + 4 <= i1; i += 4) {
    int s0 = csr[i], s1 = csr[i + 1], s2 = csr[i + 2], s3 = csr[i + 3];
    float w0 = dd * dis[s0], w1 = dd * dis[s1], w2 = dd * dis[s2], w3 = dd * dis[s3];
    float v0 = bf2f(hW[(size_t)s0 * 64 + lane]);
    float v1 = bf2f(hW[(size_t)s1 * 64 + lane]);
    float v2 = bf2f(hW[(size_t)s2 * 64 + lane]);
    float v3 = bf2f(hW[(size_t)s3 * 64 + lane]);
    if (relusrc) {
      v0 = fmaxf(v0, 0.f); v1 = fmaxf(v1, 0.f); v2 = fmaxf(v2, 0.f); v3 = fmaxf(v3, 0.f);
    }
    a += w0 * v0 + w1 * v1 + w2 * v2 + w3 * v3;
  }
  for (; i < i1; ++i) {
    int s = csr[i];
    float vv = bf2f(hW[(size_t)s * 64 + lane]);
    if (relusrc) vv = fmaxf(vv, 0.f);
    a += dd * dis[s] * vv;
  }
  agg[(size_t)d * 64 + lane] = __float2bfloat16(a);
}

// conv4: gather + bias + per-block mean-pool partial (plain stores)
__global__ void agg_gather64_final_kernel(const bf16* __restrict__ hW, const int* __restrict__ rowstart,
                                          const int* __restrict__ csr, const float* __restrict__ dis,
                                          const void* __restrict__ b, const Ctl* __restrict__ ctl,
                                          float* __restrict__ partial, int M)
{
  __shared__ float cs[64];
  const bool f32 = ctl->isfp32 != 0;
  int tid = threadIdx.x;
  if (tid < 64) cs[tid] = 0.f;
  __syncthreads();
  int gid = blockIdx.x * 256 + tid;
  int d = gid >> 6;
  int lane = gid & 63;
  if (d < M) {
    float dd = dis[d];
    float a = bf2f(hW[(size_t)d * 64 + lane]) * (dd * dd) + loadF(b, lane, f32);
    int i = rowstart[d], i1 = rowstart[d + 1];
    for (; i + 4 <= i1; i += 4) {
      int s0 = csr[i], s1 = csr[i + 1], s2 = csr[i + 2], s3 = csr[i + 3];
      float w0 = dd * dis[s0], w1 = dd * dis[s1], w2 = dd * dis[s2], w3 = dd * dis[s3];
      float v0 = bf2f(hW[(size_t)s0 * 64 + lane]);
      float v1 = bf2f(hW[(size_t)s1 * 64 + lane]);
      float v2 = bf2f(hW[(size_t)s2 * 64 + lane]);
      float v3 = bf2f(hW[(size_t)s3 * 64 + lane]);
      a += w0 * v0 + w1 * v1 + w2 * v2 + w3 * v3;
    }
    for (; i < i1; ++i) {
      int s = csr[i];
      a += dd * dis[s] * bf2f(hW[(size_t)s * 64 + lane]);
    }
    atomicAdd(&cs[lane], a);
  }
  __syncthreads();
  if (tid < 64) partial[(size_t)tid * gridDim.x + blockIdx.x] = cs[tid];
}

__global__ void reduce_out_kernel(const float* __restrict__ partial, const Ctl* __restrict__ ctl,
                                  void* __restrict__ out, int nblk)
{
  __shared__ float sh[256];
  int c = blockIdx.x;
  float s = 0.f;
  for (int j = threadIdx.x; j < nblk; j += 256) s += partial[(size_t)c * nblk + j];
  sh[threadIdx.x] = s;
  __syncthreads();
  for (int st = 128; st > 0; st >>= 1) {
    if (threadIdx.x < st) sh[threadIdx.x] += sh[threadIdx.x + st];
    __syncthreads();
  }
  if (threadIdx.x == 0) {
    float val = sh[0] / (float)K_KEEP;
    if (ctl->isfp32) ((float*)out)[c] = val;
    else             ((bf16*)out)[c] = __float2bfloat16(val);
  }
}

// ---------------- TopK select (proven fused hist+pick) ----------------

__global__ void histpick_kernel(const u64* __restrict__ keys, Ctl* ctl, int shift, int nblocks) {
  __shared__ u32 lh[256];
  __shared__ int lastflag;
  const int tid = threadIdx.x;
  lh[tid] = 0;
  __syncthreads();
  u64 prefix = ctl->prefix;
  int i = blockIdx.x * 256 + tid;
  if (i < N_NODES) {
    u64 key = keys[i];
    if ((key >> (shift + 8)) == (prefix >> (shift + 8)))
      atomicAdd(&lh[(u32)((key >> shift) & 0xFF)], 1u);
  }
  __syncthreads();
  u32 c = lh[tid];
  if (c) atomicAdd(&ctl->hist[tid], c);
  __syncthreads();
  if (tid == 0) {
    __threadfence();
    u32 old = atomicAdd(&ctl->done, 1u);
    lastflag = (old == (u32)(nblocks - 1));
  }
  __syncthreads();
  if (!lastflag) return;
  lh[tid] = atomicExch(&ctl->hist[tid], 0u);
  __syncthreads();
  if (tid == 0) {
    u32 kr = ctl->kremain;
    u32 cum = 0;
    int sel = 0;
    for (int v = 255; v >= 0; --v) {
      u32 cc = lh[v];
      if (cum + cc >= kr) { sel = v; break; }
      cum += cc;
    }
    ctl->prefix = prefix | (((u64)sel) << shift);
    ctl->kremain = kr - cum;
    ctl->done = 0u;
  }
}

__global__ void mark_kernel(const u64* __restrict__ keys, Ctl* ctl,
                            int* __restrict__ new_idx, int* __restrict__ kept)
{
  int i = blockIdx.x * 256 + threadIdx.x;
  if (i >= N_NODES) return;
  if (keys[i] >= ctl->prefix) {
    int pos = (int)atomicAdd(&ctl->cnt, 1u);
    new_idx[i] = pos;
    kept[pos] = i;
  } else {
    new_idx[i] = -1;
  }
}

__global__ void hp_kernel(const bf16* __restrict__ h, const int* __restrict__ kept,
                          const float* __restrict__ score, bf16* __restrict__ hp)
{
  int gid = blockIdx.x * 256 + threadIdx.x;
  int row = gid >> 6;
  int lane = gid & 63;
  if (row >= K_KEEP) return;
  int o = kept[row];
  float s = score[o];
  bf16x2 v = ((const bf16x2*)h)[(size_t)o * 64 + lane];
  bf16x2 w;
  w.x = __float2bfloat16(fmaxf(bf2f(v.x), 0.f) * s);
  w.y = __float2bfloat16(fmaxf(bf2f(v.y), 0.f) * s);
  ((bf16x2*)hp)[(size_t)row * 64 + lane] = w;
}

// ---------------- launch ----------------

extern "C" void kernel_launch(void* const* d_in, const int* in_sizes, int n_in,
                              void* d_out, int out_size, void* d_ws, size_t ws_size,
                              hipStream_t stream)
{
  const void* x  = d_in[0];
  const int*  ei = (const int*)d_in[1];
  const void* W1 = d_in[3];
  const void* b1 = d_in[4];
  const void* pw = d_in[5];
  const void* W2 = d_in[6];
  const void* b2 = d_in[7];
  const void* W3 = d_in[8];
  const void* b3 = d_in[9];
  const void* W4 = d_in[10];
  const void* b4 = d_in[11];

  const int* src = ei;
  const int* dst = ei + N_EDGES;

  float* F = (float*)d_ws;
  bf16*  A16       = (bf16*)F;               // N x 128 bf16
  bf16*  B16       = (bf16*)(F + 3200000);   // N x 128 bf16
  bf16*  C16       = (bf16*)(F + 6400000);   // K x 128 bf16 (also conv1's G [N x 64])
  float* dis1      = F + 9000000;            // 50000
  float* dis2      = F + 9050000;            // 40000
  float* score     = F + 9100000;            // 50000
  u64*   keys      = (u64*)(F + 9150000);    // 50000 u64
  int*   new_idx   = (int*)(F + 9250000);    // 50000
  int*   kept      = (int*)(F + 9300000);    // 40000
  int*   cnt2      = (int*)(F + 9340000);    // 40000
  int*   rowstart1 = (int*)(F + 9380000);    // 50001
  int*   rowstart2 = (int*)(F + 9430004);    // 40001
  int*   csr1      = (int*)(F + 9470008);    // 800000
  int*   csr2      = (int*)(F + 10270008);   // 800000
  Ctl*   ctl       = (Ctl*)(F + 11070008);   // ~1.1 KB
  int*   bsum      = (int*)(F + 11070500);   // 256
  int*   boff      = (int*)(F + 11070756);   // 256 (bucket offs, reused for graph2 scan)
  int*   detcnt    = (int*)(F + 11071012);   // 64
  int*   bucket_cur= (int*)(F + 11071076);   // 196
  u32*   bucketbuf = (u32*)(F + 11071332);   // 196*6144 = 1204224
  float* partial   = F + 12275556;           // 64 x 10000 (total ~51.8 MB)

  const int NB1 = (N_NODES + 255) / 256;     // 196
  const int NB2 = (K_KEEP + 255) / 256;      // 157
  const int EB2 = (N_EDGES + 2047) / 2048;   // 391 scatter blocks
  const int SGB = (K_KEEP * 16 + 255) / 256; // 2500 subgroup blocks
  const int GFB = K_KEEP / 4;                // 10000

  init_kernel<<<NB1, 256, 0, stream>>>((const unsigned short*)x, bucket_cur, detcnt, ctl);
  norm_kernel<<<1, 64, 0, stream>>>(pw, detcnt, ctl);

  // CSR graph 1 via bucket sort (no random 4B scatter)
  bucket_scatter_kernel<<<EB2, 256, 0, stream>>>(src, dst, bucket_cur, bucketbuf);
  scan_buckets_kernel<<<1, 256, 0, stream>>>(bucket_cur, boff, &rowstart1[N_NODES]);
  csr_from_buckets_kernel<<<BKT, 256, 0, stream>>>(bucketbuf, bucket_cur, boff, rowstart1, dis1, csr1);

  // conv1 (gather-first): G = A_norm . x ; h1 = G @ W1 + b1 (+fused score)
  agg_gather64_in_kernel<<<(N_NODES + 3) / 4, 256, 0, stream>>>(x, rowstart1, csr1, dis1, ctl, C16, N_NODES);
  gemm_in_kernel<<<(N_NODES + 31) / 32, 256, 0, stream>>>(C16, W1, b1, pw, B16, ctl, score, keys);

  // top-K select (6 x 8-bit radix over 48-bit keys)
  for (int p = 0; p < 6; ++p)
    histpick_kernel<<<NB1, 256, 0, stream>>>(keys, ctl, 40 - 8 * p, NB1);
  mark_kernel<<<NB1, 256, 0, stream>>>(keys, ctl, new_idx, kept);
  hp_kernel<<<(K_KEEP + 3) / 4, 256, 0, stream>>>(B16, kept, score, C16);

  // CSR graph 2: filter-compact kept rows of csr1
  cnt2_kernel<<<SGB, 256, 0, stream>>>(kept, rowstart1, csr1, new_idx, cnt2);
  block_reduce_kernel<<<NB2, 256, 0, stream>>>(cnt2, bsum, K_KEEP);
  scan_bsum_kernel<<<1, 256, 0, stream>>>(bsum, boff, NB2, &rowstart2[K_KEEP]);
  block_scanout_kernel<<<NB2, 256, 0, stream>>>(cnt2, boff, rowstart2, dis2, K_KEEP);
  fill2_kernel<<<SGB, 256, 0, stream>>>(kept, rowstart1, csr1, new_idx, rowstart2, csr2);

  // conv2: gemm-first: A = hp @ W2 ; h2 = gather(A) + b2
  gemm_128_64_kernel<<<K_KEEP / 32, 256, 0, stream>>>(C16, W2, A16, ctl, K_KEEP, 0);
  agg_gather64_kernel<<<K_KEEP / 4, 256, 0, stream>>>(A16, rowstart2, csr2, dis2, b2, ctl, B16, K_KEEP, 0, 1);

  // conv3: gather-first: G = gather(relu(h2)) ; h3 = G @ W3 + b3
  agg_gather64_kernel<<<K_KEEP / 4, 256, 0, stream>>>(B16, rowstart2, csr2, dis2, b3, ctl, A16, K_KEEP, 1, 0);
  gemm_64_128_kernel<<<K_KEEP / 32, 256, 0, stream>>>(A16, W3, b3, B16, ctl, K_KEEP);

  // conv4: gemm-first: A = relu(h3) @ W4 ; partials = gather(A) + b4
  gemm_128_64_kernel<<<K_KEEP / 32, 256, 0, stream>>>(B16, W4, A16, ctl, K_KEEP, 1);
  agg_gather64_final_kernel<<<GFB, 256, 0, stream>>>(A16, rowstart2, csr2, dis2, b4, ctl, partial, K_KEEP);

  reduce_out_kernel<<<64, 256, 0, stream>>>(partial, ctl, d_out, GFB);
}

// Round 9
// 415.030 us; speedup vs baseline: 3.0919x; 1.1743x over previous
//
#include <hip/hip_runtime.h>
#include <hip/hip_bf16.h>
#include <stdint.h>

#define N_NODES 50000
#define N_EDGES 800000
#define K_KEEP  40000
#define BKT     196        // ceil(N_NODES/256) dst-range buckets
#define BCAP    6144       // per-bucket capacity (mean 4081, +32 sigma)

typedef unsigned long long u64;
typedef unsigned int u32;
typedef unsigned short u16;
typedef __hip_bfloat16 bf16;
typedef __hip_bfloat162 bf16x2;
typedef __attribute__((ext_vector_type(8))) short short8;
typedef __attribute__((ext_vector_type(4))) float f32x4;

struct Ctl {
  u64 prefix;
  u32 kremain;
  u32 cnt;
  float inv_norm;
  u32 isfp32;
  u32 done;
  u32 pad;
  u32 hist[256];
};

__device__ __forceinline__ float bf2f(bf16 v) { return __bfloat162float(v); }
__device__ __forceinline__ float loadF(const void* p, size_t i, bool f32) {
  return f32 ? ((const float*)p)[i] : bf2f(((const bf16*)p)[i]);
}
__device__ __forceinline__ short f2bf_bits(float f) {
  bf16 t = __float2bfloat16(f);
  return *(const short*)&t;
}

// ---------------- init (+parallel dtype detect, proven R5-R8) ----------------

__global__ void init_kernel(const unsigned short* __restrict__ x16,
                            int* __restrict__ bucket_cur, int* __restrict__ detcnt, Ctl* ctl) {
  __shared__ u32 dsh[256];
  int i = blockIdx.x * 256 + threadIdx.x;
  if (i < BKT) bucket_cur[i] = i * BCAP;
  if (blockIdx.x == 0) {
    ctl->hist[threadIdx.x] = 0u;
    if (threadIdx.x == 0) { ctl->prefix = 0ull; ctl->kremain = K_KEEP; ctl->cnt = 0u; ctl->done = 0u; }
  }
  if (blockIdx.x < 64) {
    int base = blockIdx.x * 2048;
    u32 c = 0;
    for (int j = threadIdx.x; j < 2048; j += 256) {
      u32 h = x16[base + j];
      if ((h & 0x7F80u) == 0x7F80u) c++;
    }
    dsh[threadIdx.x] = c;
    __syncthreads();
    for (int s = 128; s > 0; s >>= 1) {
      if (threadIdx.x < s) dsh[threadIdx.x] += dsh[threadIdx.x + s];
      __syncthreads();
    }
    if (threadIdx.x == 0) detcnt[blockIdx.x] = (int)dsh[0];
  }
}

__global__ void norm_kernel(const void* __restrict__ pw, const int* __restrict__ detcnt, Ctl* ctl) {
  int lane = threadIdx.x;   // 64
  int dc = detcnt[lane];
  for (int off = 32; off; off >>= 1) dc += __shfl_down(dc, off);
  dc = __shfl(dc, 0);
  bool f32 = (dc >= 16);
  float v0 = loadF(pw, lane, f32);
  float v1 = loadF(pw, 64 + lane, f32);
  float s = v0 * v0 + v1 * v1;
  for (int off = 32; off; off >>= 1) s += __shfl_down(s, off);
  if (lane == 0) {
    ctl->inv_norm = 1.0f / sqrtf(s);
    ctl->isfp32 = f32 ? 1u : 0u;
  }
}

// ------------- CSR1 via bucket sort (proven R8) -------------

__global__ void bucket_scatter_kernel(const int* __restrict__ src, const int* __restrict__ dst,
                                      int* __restrict__ bucket_cur, u32* __restrict__ bucketbuf)
{
  __shared__ u32 hist[BKT];
  __shared__ u32 base[BKT];
  const int tid = threadIdx.x;
  const int e0 = blockIdx.x * 2048;
  for (int t = tid; t < BKT; t += 256) hist[t] = 0;
  __syncthreads();
  #pragma unroll
  for (int j = 0; j < 8; ++j) {
    int e = e0 + j * 256 + tid;
    if (e < N_EDGES) atomicAdd(&hist[dst[e] >> 8], 1u);
  }
  __syncthreads();
  for (int t = tid; t < BKT; t += 256) {
    u32 c = hist[t];
    base[t] = c ? (u32)atomicAdd(&bucket_cur[t], (int)c) : 0u;
    hist[t] = 0;
  }
  __syncthreads();
  #pragma unroll
  for (int j = 0; j < 8; ++j) {
    int e = e0 + j * 256 + tid;
    if (e < N_EDGES) {
      int d = dst[e];
      int b = d >> 8;
      u32 pos = base[b] + atomicAdd(&hist[b], 1u);
      bucketbuf[pos] = ((u32)src[e] << 8) | (u32)(d & 255);
    }
  }
}

__global__ void scan_buckets_kernel(const int* __restrict__ bucket_cur, int* __restrict__ boff,
                                    int* __restrict__ rowstart_n)
{
  __shared__ int sh[256];
  int tid = threadIdx.x;
  int v = (tid < BKT) ? (bucket_cur[tid] - tid * BCAP) : 0;
  sh[tid] = v;
  __syncthreads();
  for (int off = 1; off < 256; off <<= 1) {
    int t = (tid >= off) ? sh[tid - off] : 0;
    __syncthreads();
    sh[tid] += t;
    __syncthreads();
  }
  if (tid < BKT) boff[tid] = sh[tid] - v;
  if (tid == 255) *rowstart_n = sh[255];
}

__global__ void csr_from_buckets_kernel(const u32* __restrict__ bucketbuf, const int* __restrict__ bucket_cur,
                                        const int* __restrict__ boff, int* __restrict__ rowstart,
                                        float* __restrict__ dis, int* __restrict__ csr)
{
  __shared__ u32 cnt[256];
  __shared__ u32 loc[256];
  __shared__ u32 cur[256];
  const int b = blockIdx.x;
  const int tid = threadIdx.x;
  const int bc = bucket_cur[b] - b * BCAP;
  const u32* buf = bucketbuf + (size_t)b * BCAP;
  const int off0 = boff[b];
  cnt[tid] = 0;
  __syncthreads();
  for (int i = tid; i < bc; i += 256) atomicAdd(&cnt[buf[i] & 255u], 1u);
  __syncthreads();
  u32 c = cnt[tid];
  loc[tid] = c;
  __syncthreads();
  for (int off = 1; off < 256; off <<= 1) {
    u32 t = (tid >= off) ? loc[tid - off] : 0;
    __syncthreads();
    loc[tid] += t;
    __syncthreads();
  }
  int node = b * 256 + tid;
  u32 excl = loc[tid] - c;
  if (node < N_NODES) {
    rowstart[node] = off0 + (int)excl;
    dis[node] = rsqrtf(1.0f + (float)c);
  }
  cur[tid] = off0 + excl;
  __syncthreads();
  for (int i = tid; i < bc; i += 256) {
    u32 p = buf[i];
    u32 pos = atomicAdd(&cur[p & 255u], 1u);
    csr[pos] = (int)(p >> 8);
  }
}

// ---------------- hierarchical scan (graph2 only) ----------------

__global__ void block_reduce_kernel(const int* __restrict__ cnt, int* __restrict__ bsum, int n) {
  __shared__ int sh[256];
  int i = blockIdx.x * 256 + threadIdx.x;
  sh[threadIdx.x] = (i < n) ? cnt[i] : 0;
  __syncthreads();
  for (int s = 128; s > 0; s >>= 1) {
    if (threadIdx.x < s) sh[threadIdx.x] += sh[threadIdx.x + s];
    __syncthreads();
  }
  if (threadIdx.x == 0) bsum[blockIdx.x] = sh[0];
}

__global__ void scan_bsum_kernel(const int* __restrict__ bsum, int* __restrict__ boff,
                                 int nb, int* __restrict__ rowstart_n) {
  __shared__ int sh[256];
  int tid = threadIdx.x;
  int v = (tid < nb) ? bsum[tid] : 0;
  sh[tid] = v;
  __syncthreads();
  for (int off = 1; off < 256; off <<= 1) {
    int t = (tid >= off) ? sh[tid - off] : 0;
    __syncthreads();
    sh[tid] += t;
    __syncthreads();
  }
  if (tid < nb) boff[tid] = sh[tid] - v;
  if (tid == 255) *rowstart_n = sh[255];
}

__global__ void block_scanout_kernel(const int* __restrict__ cnt, const int* __restrict__ boff,
                                     int* __restrict__ rowstart, float* __restrict__ dis, int n) {
  __shared__ int sh[256];
  int tid = threadIdx.x;
  int i = blockIdx.x * 256 + tid;
  int c = (i < n) ? cnt[i] : 0;
  sh[tid] = c;
  __syncthreads();
  for (int off = 1; off < 256; off <<= 1) {
    int t = (tid >= off) ? sh[tid - off] : 0;
    __syncthreads();
    sh[tid] += t;
    __syncthreads();
  }
  if (i < n) {
    rowstart[i] = boff[blockIdx.x] + sh[tid] - c;
    dis[i] = rsqrtf(1.0f + (float)c);
  }
}

// ------- CSR2 from CSR1: filter-compact kept rows (proven R8) -------

__global__ void cnt2_kernel(const int* __restrict__ kept, const int* __restrict__ rowstart1,
                            const int* __restrict__ csr1, const int* __restrict__ new_idx,
                            int* __restrict__ cnt2)
{
  int gid = blockIdx.x * 256 + threadIdx.x;
  int kp = gid >> 4;
  int l16 = gid & 15;
  if (kp >= K_KEEP) return;
  int o = kept[kp];
  int i0 = rowstart1[o], i1 = rowstart1[o + 1];
  int c = 0;
  for (int i = i0 + l16; i < i1; i += 16) c += (new_idx[csr1[i]] >= 0);
  c += __shfl_down(c, 8, 16);
  c += __shfl_down(c, 4, 16);
  c += __shfl_down(c, 2, 16);
  c += __shfl_down(c, 1, 16);
  if (l16 == 0) cnt2[kp] = c;
}

__global__ void fill2_kernel(const int* __restrict__ kept, const int* __restrict__ rowstart1,
                             const int* __restrict__ csr1, const int* __restrict__ new_idx,
                             const int* __restrict__ rowstart2, int* __restrict__ csr2)
{
  int gid = blockIdx.x * 256 + threadIdx.x;
  int kp = gid >> 4;
  int l16 = gid & 15;
  if (kp >= K_KEEP) return;
  int o = kept[kp];
  int i0 = rowstart1[o], i1 = rowstart1[o + 1];
  int base = rowstart2[kp];
  int sub = (threadIdx.x & 63) >> 4;
  for (int ib = i0; ib < i1; ib += 16) {
    int i = ib + l16;
    int ns = -1;
    if (i < i1) ns = new_idx[csr1[i]];
    u64 bal = __ballot(ns >= 0);
    u32 m = (u32)((bal >> (sub * 16)) & 0xFFFFull);
    if (ns >= 0) {
      int rank = __popc(m & ((1u << l16) - 1u));
      csr2[base + rank] = ns;
    }
    base += __popc(m);
  }
}

// ------------- conv1 gather on input features; ILP-4 (proven R7/R8) -------------

__global__ void agg_gather64_in_kernel(const void* __restrict__ xv, const int* __restrict__ rowstart,
                                       const int* __restrict__ csr, const float* __restrict__ dis,
                                       const Ctl* __restrict__ ctl, bf16* __restrict__ G, int M)
{
  const bool f32 = ctl->isfp32 != 0;
  int gid = blockIdx.x * 256 + threadIdx.x;
  int d = gid >> 6;
  int lane = gid & 63;
  if (d >= M) return;
  float dd = dis[d];
  float a = dd * dd * loadF(xv, (size_t)d * 64 + lane, f32);
  int i = rowstart[d], i1 = rowstart[d + 1];
  for (; i + 4 <= i1; i += 4) {
    int s0 = csr[i], s1 = csr[i + 1], s2 = csr[i + 2], s3 = csr[i + 3];
    float w0 = dd * dis[s0], w1 = dd * dis[s1], w2 = dd * dis[s2], w3 = dd * dis[s3];
    float v0 = loadF(xv, (size_t)s0 * 64 + lane, f32);
    float v1 = loadF(xv, (size_t)s1 * 64 + lane, f32);
    float v2 = loadF(xv, (size_t)s2 * 64 + lane, f32);
    float v3 = loadF(xv, (size_t)s3 * 64 + lane, f32);
    a += w0 * v0 + w1 * v1 + w2 * v2 + w3 * v3;
  }
  for (; i < i1; ++i) {
    int s = csr[i];
    a += dd * dis[s] * loadF(xv, (size_t)s * 64 + lane, f32);
  }
  G[(size_t)d * 64 + lane] = __float2bfloat16(a);
}

// ---------------- MFMA GEMMs (16x16x32 bf16, fp32 acc) ----------------
// Layouts (cdna4 guide, m89/m91/m120-verified):
//   A[m=lane&15][k=quad*8+j], B[k=quad*8+j][n=lane&15], D: col=lane&15,row=quad*4+reg
// LDS strides padded to 136/72 shorts: 16B-aligned ds_read_b128, <=2-way banks.

// conv1: Y[N,128] = G[N,64] @ W1 + b1, fused pooling score/keys
__global__ void gemm_in_kernel(const bf16* __restrict__ G, const void* __restrict__ W,
                               const void* __restrict__ b, const void* __restrict__ pw,
                               bf16* __restrict__ Y, const Ctl* __restrict__ ctl,
                               float* __restrict__ score, u64* __restrict__ keys)
{
  __shared__ short Xs[64 * 72];
  __shared__ short Wt[128 * 72];
  __shared__ float bs[128];
  __shared__ float ps[128];
  const bool f32 = ctl->isfp32 != 0;
  const int tid = threadIdx.x;
  const int row0 = blockIdx.x * 64;

  for (int i = tid; i < 64 * 128; i += 256) {
    int k = i >> 7, n = i & 127;
    Wt[n * 72 + k] = f32 ? f2bf_bits(((const float*)W)[i]) : ((const short*)W)[i];
  }
  const u32* G2 = (const u32*)G;   // bf16 pair
  for (int p = tid; p < 64 * 32; p += 256) {
    int r = p >> 5, kp = p & 31;
    int gr = row0 + r;
    u32 v = (gr < N_NODES) ? G2[(size_t)gr * 32 + kp] : 0u;
    *(u32*)&Xs[r * 72 + 2 * kp] = v;
  }
  for (int i = tid; i < 128; i += 256) { bs[i] = loadF(b, i, f32); ps[i] = loadF(pw, i, f32); }
  __syncthreads();

  const int lane = tid & 63;
  const int w = tid >> 6;
  const int l16 = lane & 15;
  const int quad = lane >> 4;
  f32x4 acc[8];
  #pragma unroll
  for (int ct = 0; ct < 8; ++ct) acc[ct] = (f32x4){0.f, 0.f, 0.f, 0.f};
  const int arow = w * 16 + l16;
  #pragma unroll
  for (int kc = 0; kc < 2; ++kc) {
    short8 a = *(short8*)&Xs[arow * 72 + kc * 32 + quad * 8];
    #pragma unroll
    for (int ct = 0; ct < 8; ++ct) {
      short8 bb = *(short8*)&Wt[(ct * 16 + l16) * 72 + kc * 32 + quad * 8];
      acc[ct] = __builtin_amdgcn_mfma_f32_16x16x32_bf16(a, bb, acc[ct], 0, 0, 0);
    }
  }
  float inv_norm = ctl->inv_norm;
  #pragma unroll
  for (int r = 0; r < 4; ++r) {
    int gr = row0 + w * 16 + quad * 4 + r;
    float p = 0.f;
    #pragma unroll
    for (int ct = 0; ct < 8; ++ct) {
      int col = ct * 16 + l16;
      float h = acc[ct][r] + bs[col];
      if (gr < N_NODES) Y[(size_t)gr * 128 + col] = __float2bfloat16(h);
      p += fmaxf(h, 0.f) * ps[col];
    }
    p += __shfl_down(p, 8, 16);
    p += __shfl_down(p, 4, 16);
    p += __shfl_down(p, 2, 16);
    p += __shfl_down(p, 1, 16);
    if (l16 == 0 && gr < N_NODES) {
      float sc = tanhf(p * inv_norm);
      score[gr] = sc;
      u32 u = __float_as_uint(sc);
      u = (u & 0x80000000u) ? ~u : (u | 0x80000000u);
      keys[gr] = (((u64)u) << 16) | (u64)(0xFFFFu - (u32)gr);
    }
  }
}

// Y[M,64] = (relu?)X[M,128] @ W[128,64]; M multiple of 64
__global__ void gemm_128_64_kernel(const bf16* __restrict__ X, const void* __restrict__ W,
                                   bf16* __restrict__ Y, const Ctl* __restrict__ ctl,
                                   int M, int relu_x)
{
  __shared__ short Xs[64 * 136];
  __shared__ short Wt[64 * 136];
  const bool f32 = ctl->isfp32 != 0;
  const int tid = threadIdx.x;
  const int row0 = blockIdx.x * 64;

  for (int i = tid; i < 128 * 64; i += 256) {
    int k = i >> 6, n = i & 63;
    Wt[n * 136 + k] = f32 ? f2bf_bits(((const float*)W)[i]) : ((const short*)W)[i];
  }
  const u32* X2 = (const u32*)X;
  for (int p = tid; p < 64 * 64; p += 256) {
    int r = p >> 6, kp = p & 63;
    u32 v = X2[(size_t)(row0 + r) * 64 + kp];
    if (relu_x) {
      if (v & 0x8000u) v &= 0xFFFF0000u;
      if (v & 0x80000000u) v &= 0x0000FFFFu;
    }
    *(u32*)&Xs[r * 136 + 2 * kp] = v;
  }
  __syncthreads();

  const int lane = tid & 63;
  const int w = tid >> 6;
  const int l16 = lane & 15;
  const int quad = lane >> 4;
  f32x4 acc[4];
  #pragma unroll
  for (int ct = 0; ct < 4; ++ct) acc[ct] = (f32x4){0.f, 0.f, 0.f, 0.f};
  const int arow = w * 16 + l16;
  #pragma unroll
  for (int kc = 0; kc < 4; ++kc) {
    short8 a = *(short8*)&Xs[arow * 136 + kc * 32 + quad * 8];
    #pragma unroll
    for (int ct = 0; ct < 4; ++ct) {
      short8 bb = *(short8*)&Wt[(ct * 16 + l16) * 136 + kc * 32 + quad * 8];
      acc[ct] = __builtin_amdgcn_mfma_f32_16x16x32_bf16(a, bb, acc[ct], 0, 0, 0);
    }
  }
  #pragma unroll
  for (int ct = 0; ct < 4; ++ct)
    #pragma unroll
    for (int r = 0; r < 4; ++r) {
      int gr = row0 + w * 16 + quad * 4 + r;
      Y[(size_t)gr * 64 + ct * 16 + l16] = __float2bfloat16(acc[ct][r]);
    }
}

// conv3: Y[M,128] = X[M,64] @ W[64,128] + b; M multiple of 64
__global__ void gemm_64_128_kernel(const bf16* __restrict__ X, const void* __restrict__ W,
                                   const void* __restrict__ b, bf16* __restrict__ Y,
                                   const Ctl* __restrict__ ctl, int M)
{
  __shared__ short Xs[64 * 72];
  __shared__ short Wt[128 * 72];
  __shared__ float bs[128];
  const bool f32 = ctl->isfp32 != 0;
  const int tid = threadIdx.x;
  const int row0 = blockIdx.x * 64;

  for (int i = tid; i < 64 * 128; i += 256) {
    int k = i >> 7, n = i & 127;
    Wt[n * 72 + k] = f32 ? f2bf_bits(((const float*)W)[i]) : ((const short*)W)[i];
  }
  const u32* X2 = (const u32*)X;
  for (int p = tid; p < 64 * 32; p += 256) {
    int r = p >> 5, kp = p & 31;
    *(u32*)&Xs[r * 72 + 2 * kp] = X2[(size_t)(row0 + r) * 32 + kp];
  }
  for (int i = tid; i < 128; i += 256) bs[i] = loadF(b, i, f32);
  __syncthreads();

  const int lane = tid & 63;
  const int w = tid >> 6;
  const int l16 = lane & 15;
  const int quad = lane >> 4;
  f32x4 acc[8];
  #pragma unroll
  for (int ct = 0; ct < 8; ++ct) acc[ct] = (f32x4){0.f, 0.f, 0.f, 0.f};
  const int arow = w * 16 + l16;
  #pragma unroll
  for (int kc = 0; kc < 2; ++kc) {
    short8 a = *(short8*)&Xs[arow * 72 + kc * 32 + quad * 8];
    #pragma unroll
    for (int ct = 0; ct < 8; ++ct) {
      short8 bb = *(short8*)&Wt[(ct * 16 + l16) * 72 + kc * 32 + quad * 8];
      acc[ct] = __builtin_amdgcn_mfma_f32_16x16x32_bf16(a, bb, acc[ct], 0, 0, 0);
    }
  }
  #pragma unroll
  for (int ct = 0; ct < 8; ++ct)
    #pragma unroll
    for (int r = 0; r < 4; ++r) {
      int gr = row0 + w * 16 + quad * 4 + r;
      int col = ct * 16 + l16;
      Y[(size_t)gr * 128 + col] = __float2bfloat16(acc[ct][r] + bs[col]);
    }
}

// --------- gather on bf16 rows (64 ch), optional relu/bias; ILP-4 ---------

__global__ void agg_gather64_kernel(const bf16* __restrict__ hW, const int* __restrict__ rowstart,
                                    const int* __restrict__ csr, const float* __restrict__ dis,
                                    const void* __restrict__ b, const Ctl* __restrict__ ctl,
                                    bf16* __restrict__ agg, int M, int relusrc, int addbias)
{
  const bool f32 = ctl->isfp32 != 0;
  int gid = blockIdx.x * 256 + threadIdx.x;
  int d = gid >> 6;
  int lane = gid & 63;
  if (d >= M) return;
  float dd = dis[d];
  float v = bf2f(hW[(size_t)d * 64 + lane]);
  if (relusrc) v = fmaxf(v, 0.f);
  float a = v * dd * dd + (addbias ? loadF(b, lane, f32) : 0.f);
  int i = rowstart[d], i1 = rowstart[d + 1];
  for (; i + 4 <= i1; i += 4) {
    int s0 = csr[i], s1 = csr[i + 1], s2 = csr[i + 2], s3 = csr[i + 3];
    float w0 = dd * dis[s0], w1 = dd * dis[s1], w2 = dd * dis[s2], w3 = dd * dis[s3];
    float v0 = bf2f(hW[(size_t)s0 * 64 + lane]);
    float v1 = bf2f(hW[(size_t)s1 * 64 + lane]);
    float v2 = bf2f(hW[(size_t)s2 * 64 + lane]);
    float v3 = bf2f(hW[(size_t)s3 * 64 + lane]);
    if (relusrc) {
      v0 = fmaxf(v0, 0.f); v1 = fmaxf(v1, 0.f); v2 = fmaxf(v2, 0.f); v3 = fmaxf(v3, 0.f);
    }
    a += w0 * v0 + w1 * v1 + w2 * v2 + w3 * v3;
  }
  for (; i < i1; ++i) {
    int s = csr[i];
    float vv = bf2f(hW[(size_t)s * 64 + lane]);
    if (relusrc) vv = fmaxf(vv, 0.f);
    a += dd * dis[s] * vv;
  }
  agg[(size_t)d * 64 + lane] = __float2bfloat16(a);
}

// conv4: gather + bias + per-block mean-pool partial (plain stores)
__global__ void agg_gather64_final_kernel(const bf16* __restrict__ hW, const int* __restrict__ rowstart,
                                          const int* __restrict__ csr, const float* __restrict__ dis,
                                          const void* __restrict__ b, const Ctl* __restrict__ ctl,
                                          float* __restrict__ partial, int M)
{
  __shared__ float cs[64];
  const bool f32 = ctl->isfp32 != 0;
  int tid = threadIdx.x;
  if (tid < 64) cs[tid] = 0.f;
  __syncthreads();
  int gid = blockIdx.x * 256 + tid;
  int d = gid >> 6;
  int lane = gid & 63;
  if (d < M) {
    float dd = dis[d];
    float a = bf2f(hW[(size_t)d * 64 + lane]) * (dd * dd) + loadF(b, lane, f32);
    int i = rowstart[d], i1 = rowstart[d + 1];
    for (; i + 4 <= i1; i += 4) {
      int s0 = csr[i], s1 = csr[i + 1], s2 = csr[i + 2], s3 = csr[i + 3];
      float w0 = dd * dis[s0], w1 = dd * dis[s1], w2 = dd * dis[s2], w3 = dd * dis[s3];
      float v0 = bf2f(hW[(size_t)s0 * 64 + lane]);
      float v1 = bf2f(hW[(size_t)s1 * 64 + lane]);
      float v2 = bf2f(hW[(size_t)s2 * 64 + lane]);
      float v3 = bf2f(hW[(size_t)s3 * 64 + lane]);
      a += w0 * v0 + w1 * v1 + w2 * v2 + w3 * v3;
    }
    for (; i < i1; ++i) {
      int s = csr[i];
      a += dd * dis[s] * bf2f(hW[(size_t)s * 64 + lane]);
    }
    atomicAdd(&cs[lane], a);
  }
  __syncthreads();
  if (tid < 64) partial[(size_t)tid * gridDim.x + blockIdx.x] = cs[tid];
}

__global__ void reduce_out_kernel(const float* __restrict__ partial, const Ctl* __restrict__ ctl,
                                  void* __restrict__ out, int nblk)
{
  __shared__ float sh[256];
  int c = blockIdx.x;
  float s = 0.f;
  for (int j = threadIdx.x; j < nblk; j += 256) s += partial[(size_t)c * nblk + j];
  sh[threadIdx.x] = s;
  __syncthreads();
  for (int st = 128; st > 0; st >>= 1) {
    if (threadIdx.x < st) sh[threadIdx.x] += sh[threadIdx.x + st];
    __syncthreads();
  }
  if (threadIdx.x == 0) {
    float val = sh[0] / (float)K_KEEP;
    if (ctl->isfp32) ((float*)out)[c] = val;
    else             ((bf16*)out)[c] = __float2bfloat16(val);
  }
}

// ---------------- TopK select (proven fused hist+pick) ----------------

__global__ void histpick_kernel(const u64* __restrict__ keys, Ctl* ctl, int shift, int nblocks) {
  __shared__ u32 lh[256];
  __shared__ int lastflag;
  const int tid = threadIdx.x;
  lh[tid] = 0;
  __syncthreads();
  u64 prefix = ctl->prefix;
  int i = blockIdx.x * 256 + tid;
  if (i < N_NODES) {
    u64 key = keys[i];
    if ((key >> (shift + 8)) == (prefix >> (shift + 8)))
      atomicAdd(&lh[(u32)((key >> shift) & 0xFF)], 1u);
  }
  __syncthreads();
  u32 c = lh[tid];
  if (c) atomicAdd(&ctl->hist[tid], c);
  __syncthreads();
  if (tid == 0) {
    __threadfence();
    u32 old = atomicAdd(&ctl->done, 1u);
    lastflag = (old == (u32)(nblocks - 1));
  }
  __syncthreads();
  if (!lastflag) return;
  lh[tid] = atomicExch(&ctl->hist[tid], 0u);
  __syncthreads();
  if (tid == 0) {
    u32 kr = ctl->kremain;
    u32 cum = 0;
    int sel = 0;
    for (int v = 255; v >= 0; --v) {
      u32 cc = lh[v];
      if (cum + cc >= kr) { sel = v; break; }
      cum += cc;
    }
    ctl->prefix = prefix | (((u64)sel) << shift);
    ctl->kremain = kr - cum;
    ctl->done = 0u;
  }
}

__global__ void mark_kernel(const u64* __restrict__ keys, Ctl* ctl,
                            int* __restrict__ new_idx, int* __restrict__ kept)
{
  int i = blockIdx.x * 256 + threadIdx.x;
  if (i >= N_NODES) return;
  if (keys[i] >= ctl->prefix) {
    int pos = (int)atomicAdd(&ctl->cnt, 1u);
    new_idx[i] = pos;
    kept[pos] = i;
  } else {
    new_idx[i] = -1;
  }
}

__global__ void hp_kernel(const bf16* __restrict__ h, const int* __restrict__ kept,
                          const float* __restrict__ score, bf16* __restrict__ hp)
{
  int gid = blockIdx.x * 256 + threadIdx.x;
  int row = gid >> 6;
  int lane = gid & 63;
  if (row >= K_KEEP) return;
  int o = kept[row];
  float s = score[o];
  bf16x2 v = ((const bf16x2*)h)[(size_t)o * 64 + lane];
  bf16x2 w;
  w.x = __float2bfloat16(fmaxf(bf2f(v.x), 0.f) * s);
  w.y = __float2bfloat16(fmaxf(bf2f(v.y), 0.f) * s);
  ((bf16x2*)hp)[(size_t)row * 64 + lane] = w;
}

// ---------------- launch ----------------

extern "C" void kernel_launch(void* const* d_in, const int* in_sizes, int n_in,
                              void* d_out, int out_size, void* d_ws, size_t ws_size,
                              hipStream_t stream)
{
  const void* x  = d_in[0];
  const int*  ei = (const int*)d_in[1];
  const void* W1 = d_in[3];
  const void* b1 = d_in[4];
  const void* pw = d_in[5];
  const void* W2 = d_in[6];
  const void* b2 = d_in[7];
  const void* W3 = d_in[8];
  const void* b3 = d_in[9];
  const void* W4 = d_in[10];
  const void* b4 = d_in[11];

  const int* src = ei;
  const int* dst = ei + N_EDGES;

  float* F = (float*)d_ws;
  bf16*  A16       = (bf16*)F;               // N x 128 bf16
  bf16*  B16       = (bf16*)(F + 3200000);   // N x 128 bf16
  bf16*  C16       = (bf16*)(F + 6400000);   // K x 128 bf16 (also conv1's G [N x 64])
  float* dis1      = F + 9000000;            // 50000
  float* dis2      = F + 9050000;            // 40000
  float* score     = F + 9100000;            // 50000
  u64*   keys      = (u64*)(F + 9150000);    // 50000 u64
  int*   new_idx   = (int*)(F + 9250000);    // 50000
  int*   kept      = (int*)(F + 9300000);    // 40000
  int*   cnt2      = (int*)(F + 9340000);    // 40000
  int*   rowstart1 = (int*)(F + 9380000);    // 50001
  int*   rowstart2 = (int*)(F + 9430004);    // 40001
  int*   csr1      = (int*)(F + 9470008);    // 800000
  int*   csr2      = (int*)(F + 10270008);   // 800000
  Ctl*   ctl       = (Ctl*)(F + 11070008);   // ~1.1 KB
  int*   bsum      = (int*)(F + 11070500);   // 256
  int*   boff      = (int*)(F + 11070756);   // 256
  int*   detcnt    = (int*)(F + 11071012);   // 64
  int*   bucket_cur= (int*)(F + 11071076);   // 196
  u32*   bucketbuf = (u32*)(F + 11071332);   // 196*6144
  float* partial   = F + 12275556;           // 64 x 10000

  const int NB1 = (N_NODES + 255) / 256;     // 196
  const int NB2 = (K_KEEP + 255) / 256;      // 157
  const int EB2 = (N_EDGES + 2047) / 2048;   // 391
  const int SGB = (K_KEEP * 16 + 255) / 256; // 2500
  const int GFB = K_KEEP / 4;                // 10000

  init_kernel<<<NB1, 256, 0, stream>>>((const unsigned short*)x, bucket_cur, detcnt, ctl);
  norm_kernel<<<1, 64, 0, stream>>>(pw, detcnt, ctl);

  // CSR graph 1 via bucket sort
  bucket_scatter_kernel<<<EB2, 256, 0, stream>>>(src, dst, bucket_cur, bucketbuf);
  scan_buckets_kernel<<<1, 256, 0, stream>>>(bucket_cur, boff, &rowstart1[N_NODES]);
  csr_from_buckets_kernel<<<BKT, 256, 0, stream>>>(bucketbuf, bucket_cur, boff, rowstart1, dis1, csr1);

  // conv1 (gather-first): G = A_norm . x ; h1 = G @ W1 + b1 (+fused score)
  agg_gather64_in_kernel<<<(N_NODES + 3) / 4, 256, 0, stream>>>(x, rowstart1, csr1, dis1, ctl, C16, N_NODES);
  gemm_in_kernel<<<(N_NODES + 63) / 64, 256, 0, stream>>>(C16, W1, b1, pw, B16, ctl, score, keys);

  // top-K select (6 x 8-bit radix over 48-bit keys)
  for (int p = 0; p < 6; ++p)
    histpick_kernel<<<NB1, 256, 0, stream>>>(keys, ctl, 40 - 8 * p, NB1);
  mark_kernel<<<NB1, 256, 0, stream>>>(keys, ctl, new_idx, kept);
  hp_kernel<<<(K_KEEP + 3) / 4, 256, 0, stream>>>(B16, kept, score, C16);

  // CSR graph 2: filter-compact kept rows of csr1
  cnt2_kernel<<<SGB, 256, 0, stream>>>(kept, rowstart1, csr1, new_idx, cnt2);
  block_reduce_kernel<<<NB2, 256, 0, stream>>>(cnt2, bsum, K_KEEP);
  scan_bsum_kernel<<<1, 256, 0, stream>>>(bsum, boff, NB2, &rowstart2[K_KEEP]);
  block_scanout_kernel<<<NB2, 256, 0, stream>>>(cnt2, boff, rowstart2, dis2, K_KEEP);
  fill2_kernel<<<SGB, 256, 0, stream>>>(kept, rowstart1, csr1, new_idx, rowstart2, csr2);

  // conv2: gemm-first: A = hp @ W2 ; h2 = gather(A) + b2
  gemm_128_64_kernel<<<K_KEEP / 64, 256, 0, stream>>>(C16, W2, A16, ctl, K_KEEP, 0);
  agg_gather64_kernel<<<K_KEEP / 4, 256, 0, stream>>>(A16, rowstart2, csr2, dis2, b2, ctl, B16, K_KEEP, 0, 1);

  // conv3: gather-first: G = gather(relu(h2)) ; h3 = G @ W3 + b3
  agg_gather64_kernel<<<K_KEEP / 4, 256, 0, stream>>>(B16, rowstart2, csr2, dis2, b3, ctl, A16, K_KEEP, 1, 0);
  gemm_64_128_kernel<<<K_KEEP / 64, 256, 0, stream>>>(A16, W3, b3, B16, ctl, K_KEEP);

  // conv4: gemm-first: A = relu(h3) @ W4 ; partials = gather(A) + b4
  gemm_128_64_kernel<<<K_KEEP / 64, 256, 0, stream>>>(B16, W4, A16, ctl, K_KEEP, 1);
  agg_gather64_final_kernel<<<GFB, 256, 0, stream>>>(A16, rowstart2, csr2, dis2, b4, ctl, partial, K_KEEP);

  reduce_out_kernel<<<64, 256, 0, stream>>>(partial, ctl, d_out, GFB);
}